// Round 2
// baseline (442.953 us; speedup 1.0000x reference)
//
#include <hip/hip_runtime.h>

// Factorial HMM forward (3 chains x 8 states = 512 states, M=4, T=65536).
// Probability-domain scaled forward recurrence; transition applied as three
// 8x8 tensor contractions (chain-0 in-lane over registers, chains 1/2
// cross-lane via ds_bpermute). Chunked-parallel over T with burn-in.
// One wave (64 lanes) per chunk; lane l holds states s = r*64 + l, r=0..7.
// R1: 4 waves/SIMD occupancy (4096 chunks, 256-thr blocks) + BURN 128->8.

#define NCHUNK 4096
#define CLEN   16          // NCHUNK * CLEN == 65536
#define BURN   8

__device__ __forceinline__ float wave_reduce_max(float v) {
#pragma unroll
  for (int m = 32; m >= 1; m >>= 1) v = fmaxf(v, __shfl_xor(v, m, 64));
  return v;
}
__device__ __forceinline__ float wave_reduce_sum(float v) {
#pragma unroll
  for (int m = 32; m >= 1; m >>= 1) v += __shfl_xor(v, m, 64);
  return v;
}

__global__ __launch_bounds__(256, 4)
void hmm_fwd_chunk(const int* __restrict__ x,
                   const float* __restrict__ lam0, const float* __restrict__ lam1,
                   const float* __restrict__ lam2,
                   const float* __restrict__ logA0, const float* __restrict__ logA1,
                   const float* __restrict__ logA2,
                   const float* __restrict__ logp0, const float* __restrict__ logp1,
                   const float* __restrict__ logp2,
                   double* __restrict__ accum)
{
  const int l = threadIdx.x & 63;                          // lane 0..63
  const int chunk = blockIdx.x * 4 + (threadIdx.x >> 6);   // 0..NCHUNK-1
  const int j1 = l >> 3;            // chain-1 state of this lane
  const int j2 = l & 7;             // chain-2 state of this lane

  // log(n!) table for n = x in [0,19]  (lgamma(x+1))
  __shared__ float lgam[20];
  if (threadIdx.x == 0) {
    lgam[0]  = 0.0f;          lgam[1]  = 0.0f;
    lgam[2]  = 0.69314718f;   lgam[3]  = 1.79175947f;
    lgam[4]  = 3.17805383f;   lgam[5]  = 4.78749174f;
    lgam[6]  = 6.57925121f;   lgam[7]  = 8.52516136f;
    lgam[8]  = 10.60460290f;  lgam[9]  = 12.80182748f;
    lgam[10] = 15.10441257f;  lgam[11] = 17.50230785f;
    lgam[12] = 19.98721450f;  lgam[13] = 22.55216385f;
    lgam[14] = 25.19122118f;  lgam[15] = 27.89927138f;
    lgam[16] = 30.67186011f;  lgam[17] = 33.50507345f;
    lgam[18] = 36.39544521f;  lgam[19] = 39.33988419f;
  }
  __syncthreads();

  // ---- transition probability tables: T = exp(log_softmax(logA, axis=0)) ----
  // Chain 0: full 8x8, lane-uniform (contracted in-lane over registers).
  float T0f[8][8];
#pragma unroll
  for (int k = 0; k < 8; ++k) {
    float m = logA0[k];
#pragma unroll
    for (int j = 1; j < 8; ++j) m = fmaxf(m, logA0[j * 8 + k]);
    float s = 0.f;
#pragma unroll
    for (int j = 0; j < 8; ++j) s += __expf(logA0[j * 8 + k] - m);
    float inv = 1.0f / s;
#pragma unroll
    for (int j = 0; j < 8; ++j) T0f[j][k] = __expf(logA0[j * 8 + k] - m) * inv;
  }
  // Chain 1: lane keeps only its output row T1[j1, k].
  float T1r[8];
#pragma unroll
  for (int k = 0; k < 8; ++k) {
    float m = logA1[k];
#pragma unroll
    for (int j = 1; j < 8; ++j) m = fmaxf(m, logA1[j * 8 + k]);
    float s = 0.f;
#pragma unroll
    for (int j = 0; j < 8; ++j) s += __expf(logA1[j * 8 + k] - m);
    T1r[k] = __expf(logA1[j1 * 8 + k] - m) / s;
  }
  // Chain 2: lane keeps row T2[j2, k].
  float T2r[8];
#pragma unroll
  for (int k = 0; k < 8; ++k) {
    float m = logA2[k];
#pragma unroll
    for (int j = 1; j < 8; ++j) m = fmaxf(m, logA2[j * 8 + k]);
    float s = 0.f;
#pragma unroll
    for (int j = 0; j < 8; ++j) s += __expf(logA2[j * 8 + k] - m);
    T2r[k] = __expf(logA2[j2 * 8 + k] - m) / s;
  }

  // ---- emission tables: log(lambdaC) and sum(lambdaC) for lane's 8 states ----
  float Lt[8][4], sumLam[8];
#pragma unroll
  for (int r = 0; r < 8; ++r) {
    float s = 0.f;
#pragma unroll
    for (int m = 0; m < 4; ++m) {
      float lam = lam0[r * 4 + m] + lam1[j1 * 4 + m] + lam2[j2 * 4 + m];
      Lt[r][m] = __logf(lam);
      s += lam;
    }
    sumLam[r] = s;
  }

  // bpermute byte addresses (loop-invariant)
  int a1[8], a2[8];
#pragma unroll
  for (int k = 0; k < 8; ++k) {
    a1[k] = (k * 8 + j2) << 2;   // gather over k1 (keep k2)
    a2[k] = (j1 * 8 + k) << 2;   // gather over k2 (keep j1)
  }

  const int tstart = chunk * CLEN;
  const int tend = tstart + CLEN;

  float v[8];
  double zacc = 0.0;
  int t;

  // emission log-prob (incl. -C_t) for all 8 register states
  auto emis = [&](const int4 xi, float e[8]) {
    const float xf0 = (float)xi.x, xf1 = (float)xi.y,
                xf2 = (float)xi.z, xf3 = (float)xi.w;
    const float Ct = lgam[xi.x] + lgam[xi.y] + lgam[xi.z] + lgam[xi.w];
#pragma unroll
    for (int r = 0; r < 8; ++r) {
      float a = -sumLam[r] - Ct;
      a = fmaf(xf0, Lt[r][0], a);
      a = fmaf(xf1, Lt[r][1], a);
      a = fmaf(xf2, Lt[r][2], a);
      a = fmaf(xf3, Lt[r][3], a);
      e[r] = a;
    }
  };

  if (chunk == 0) {
    // exact init from prior at t=0
    float lp0[8];
    {
      float m = logp0[0];
#pragma unroll
      for (int j = 1; j < 8; ++j) m = fmaxf(m, logp0[j]);
      float s = 0.f;
#pragma unroll
      for (int j = 0; j < 8; ++j) s += __expf(logp0[j] - m);
      float lg = m + __logf(s);
#pragma unroll
      for (int j = 0; j < 8; ++j) lp0[j] = logp0[j] - lg;
    }
    float lp1v, lp2v;
    {
      float m = logp1[0];
#pragma unroll
      for (int j = 1; j < 8; ++j) m = fmaxf(m, logp1[j]);
      float s = 0.f;
#pragma unroll
      for (int j = 0; j < 8; ++j) s += __expf(logp1[j] - m);
      lp1v = logp1[j1] - (m + __logf(s));
    }
    {
      float m = logp2[0];
#pragma unroll
      for (int j = 1; j < 8; ++j) m = fmaxf(m, logp2[j]);
      float s = 0.f;
#pragma unroll
      for (int j = 0; j < 8; ++j) s += __expf(logp2[j] - m);
      lp2v = logp2[j2] - (m + __logf(s));
    }
    float e[8];
    emis(*reinterpret_cast<const int4*>(x), e);
    float a[8];
    float mx = -3.0e38f;
#pragma unroll
    for (int r = 0; r < 8; ++r) {
      a[r] = lp0[r] + lp1v + lp2v + e[r];
      mx = fmaxf(mx, a[r]);
    }
    mx = wave_reduce_max(mx);
#pragma unroll
    for (int r = 0; r < 8; ++r) v[r] = __expf(a[r] - mx);
    zacc = (double)mx;
    t = 1;
  } else {
    // burn-in from a uniform (unnormalized) message
#pragma unroll
    for (int r = 0; r < 8; ++r) v[r] = 1.0f;
    t = tstart - BURN;
    if (t < 0) t = 0;
  }

  auto step = [&](int tt, bool accumulate) {
    const int4 xi = *reinterpret_cast<const int4*>(x + 4 * tt);
    float e[8];
    emis(xi, e);

    // ---- chain-0 contraction (in-lane over registers) ----
    float q[8];
#pragma unroll
    for (int j = 0; j < 8; ++j) {
      float a = T0f[j][0] * v[0];
#pragma unroll
      for (int k = 1; k < 8; ++k) a = fmaf(T0f[j][k], v[k], a);
      q[j] = a;
    }
    // ---- chain-1 contraction (cross-lane, lane bits 3..5) ----
#pragma unroll
    for (int j = 0; j < 8; ++j) {
      float a = 0.f;
#pragma unroll
      for (int k = 0; k < 8; ++k) {
        float g = __int_as_float(
            __builtin_amdgcn_ds_bpermute(a1[k], __float_as_int(q[j])));
        a = fmaf(T1r[k], g, a);
      }
      q[j] = a;
    }
    // ---- chain-2 contraction (cross-lane, lane bits 0..2) ----
#pragma unroll
    for (int j = 0; j < 8; ++j) {
      float a = 0.f;
#pragma unroll
      for (int k = 0; k < 8; ++k) {
        float g = __int_as_float(
            __builtin_amdgcn_ds_bpermute(a2[k], __float_as_int(q[j])));
        a = fmaf(T2r[k], g, a);
      }
      q[j] = a;
    }

    // ---- emission multiply with max-shift (range safety), then renormalize ----
    float me = e[0];
#pragma unroll
    for (int r = 1; r < 8; ++r) me = fmaxf(me, e[r]);
    me = wave_reduce_max(me);

    float c = 0.f;
#pragma unroll
    for (int r = 0; r < 8; ++r) {
      float tl = q[r] * __expf(e[r] - me);
      v[r] = tl;
      c = fmaxf(c, tl);
    }
    c = wave_reduce_max(c);
    const float rinv = __builtin_amdgcn_rcpf(c);
#pragma unroll
    for (int r = 0; r < 8; ++r) v[r] *= rinv;

    if (accumulate) zacc += (double)(__logf(c) + me);
  };

  for (; t < tstart; ++t) step(t, false);  // burn-in (discard normalizers)
  for (; t < tend; ++t) step(t, true);     // accumulate log c_t

  if (chunk == NCHUNK - 1) {
    float s = 0.f;
#pragma unroll
    for (int r = 0; r < 8; ++r) s += v[r];
    s = wave_reduce_sum(s);
    zacc += (double)__logf(s);
  }

  if (l == 0) atomicAdd(accum, zacc);
}

__global__ void zero_acc_kernel(double* acc) {
  if (threadIdx.x == 0) *acc = 0.0;
}
__global__ void finalize_kernel(const double* __restrict__ acc,
                                float* __restrict__ out) {
  if (threadIdx.x == 0) out[0] = (float)(*acc);
}

extern "C" void kernel_launch(void* const* d_in, const int* in_sizes, int n_in,
                              void* d_out, int out_size, void* d_ws, size_t ws_size,
                              hipStream_t stream) {
  const int*   x     = (const int*)d_in[0];
  const float* lam0  = (const float*)d_in[1];
  const float* lam1  = (const float*)d_in[2];
  const float* lam2  = (const float*)d_in[3];
  const float* logA0 = (const float*)d_in[4];
  const float* logA1 = (const float*)d_in[5];
  const float* logA2 = (const float*)d_in[6];
  const float* logp0 = (const float*)d_in[7];
  const float* logp1 = (const float*)d_in[8];
  const float* logp2 = (const float*)d_in[9];
  double* acc = (double*)d_ws;
  float*  out = (float*)d_out;

  zero_acc_kernel<<<1, 64, 0, stream>>>(acc);
  hmm_fwd_chunk<<<NCHUNK / 4, 256, 0, stream>>>(x, lam0, lam1, lam2,
                                                logA0, logA1, logA2,
                                                logp0, logp1, logp2, acc);
  finalize_kernel<<<1, 64, 0, stream>>>(acc, out);
}

// Round 3
// 172.238 us; speedup vs baseline: 2.5717x; 2.5717x over previous
//
#include <hip/hip_runtime.h>

// Factorial HMM forward (3 chains x 8 states = 512 states, M=4, T=65536).
// Probability-domain scaled forward recurrence; transition applied as three
// 8x8 tensor contractions (chain-0 in-lane over registers, chains 1/2
// cross-lane via ds_bpermute). Chunked-parallel over T with burn-in.
// One wave (64 lanes) per chunk; lane l holds states s = r*64 + l, r=0..7.
// R2: 4096 single-wave blocks (16/CU -> 4 waves/SIMD) with the R0 register
// regime (launch_bounds(64,1) -> 120 VGPR, no spill). R1's (256,4) made the
// allocator shrink to 64 VGPR and spill 870 MB/launch to scratch.

#define NCHUNK 4096
#define CLEN   16          // NCHUNK * CLEN == 65536
#define BURN   8

__device__ __forceinline__ float wave_reduce_max(float v) {
#pragma unroll
  for (int m = 32; m >= 1; m >>= 1) v = fmaxf(v, __shfl_xor(v, m, 64));
  return v;
}
__device__ __forceinline__ float wave_reduce_sum(float v) {
#pragma unroll
  for (int m = 32; m >= 1; m >>= 1) v += __shfl_xor(v, m, 64);
  return v;
}

__global__ __launch_bounds__(64, 1)
void hmm_fwd_chunk(const int* __restrict__ x,
                   const float* __restrict__ lam0, const float* __restrict__ lam1,
                   const float* __restrict__ lam2,
                   const float* __restrict__ logA0, const float* __restrict__ logA1,
                   const float* __restrict__ logA2,
                   const float* __restrict__ logp0, const float* __restrict__ logp1,
                   const float* __restrict__ logp2,
                   double* __restrict__ accum)
{
  const int l = threadIdx.x;        // 0..63
  const int chunk = blockIdx.x;     // 0..NCHUNK-1
  const int j1 = l >> 3;            // chain-1 state of this lane
  const int j2 = l & 7;             // chain-2 state of this lane

  // log(n!) table for n = x in [0,19]  (lgamma(x+1))
  __shared__ float lgam[20];
  if (l == 0) {
    lgam[0]  = 0.0f;          lgam[1]  = 0.0f;
    lgam[2]  = 0.69314718f;   lgam[3]  = 1.79175947f;
    lgam[4]  = 3.17805383f;   lgam[5]  = 4.78749174f;
    lgam[6]  = 6.57925121f;   lgam[7]  = 8.52516136f;
    lgam[8]  = 10.60460290f;  lgam[9]  = 12.80182748f;
    lgam[10] = 15.10441257f;  lgam[11] = 17.50230785f;
    lgam[12] = 19.98721450f;  lgam[13] = 22.55216385f;
    lgam[14] = 25.19122118f;  lgam[15] = 27.89927138f;
    lgam[16] = 30.67186011f;  lgam[17] = 33.50507345f;
    lgam[18] = 36.39544521f;  lgam[19] = 39.33988419f;
  }
  __syncthreads();

  // ---- transition probability tables: T = exp(log_softmax(logA, axis=0)) ----
  // Chain 0: full 8x8, lane-uniform (contracted in-lane over registers).
  float T0f[8][8];
#pragma unroll
  for (int k = 0; k < 8; ++k) {
    float m = logA0[k];
#pragma unroll
    for (int j = 1; j < 8; ++j) m = fmaxf(m, logA0[j * 8 + k]);
    float s = 0.f;
#pragma unroll
    for (int j = 0; j < 8; ++j) s += __expf(logA0[j * 8 + k] - m);
    float inv = 1.0f / s;
#pragma unroll
    for (int j = 0; j < 8; ++j) T0f[j][k] = __expf(logA0[j * 8 + k] - m) * inv;
  }
  // Chain 1: lane keeps only its output row T1[j1, k].
  float T1r[8];
#pragma unroll
  for (int k = 0; k < 8; ++k) {
    float m = logA1[k];
#pragma unroll
    for (int j = 1; j < 8; ++j) m = fmaxf(m, logA1[j * 8 + k]);
    float s = 0.f;
#pragma unroll
    for (int j = 0; j < 8; ++j) s += __expf(logA1[j * 8 + k] - m);
    T1r[k] = __expf(logA1[j1 * 8 + k] - m) / s;
  }
  // Chain 2: lane keeps row T2[j2, k].
  float T2r[8];
#pragma unroll
  for (int k = 0; k < 8; ++k) {
    float m = logA2[k];
#pragma unroll
    for (int j = 1; j < 8; ++j) m = fmaxf(m, logA2[j * 8 + k]);
    float s = 0.f;
#pragma unroll
    for (int j = 0; j < 8; ++j) s += __expf(logA2[j * 8 + k] - m);
    T2r[k] = __expf(logA2[j2 * 8 + k] - m) / s;
  }

  // ---- emission tables: log(lambdaC) and sum(lambdaC) for lane's 8 states ----
  float Lt[8][4], sumLam[8];
#pragma unroll
  for (int r = 0; r < 8; ++r) {
    float s = 0.f;
#pragma unroll
    for (int m = 0; m < 4; ++m) {
      float lam = lam0[r * 4 + m] + lam1[j1 * 4 + m] + lam2[j2 * 4 + m];
      Lt[r][m] = __logf(lam);
      s += lam;
    }
    sumLam[r] = s;
  }

  // bpermute byte addresses (loop-invariant)
  int a1[8], a2[8];
#pragma unroll
  for (int k = 0; k < 8; ++k) {
    a1[k] = (k * 8 + j2) << 2;   // gather over k1 (keep k2)
    a2[k] = (j1 * 8 + k) << 2;   // gather over k2 (keep j1)
  }

  const int tstart = chunk * CLEN;
  const int tend = tstart + CLEN;

  float v[8];
  double zacc = 0.0;
  int t;

  // emission log-prob (incl. -C_t) for all 8 register states
  auto emis = [&](const int4 xi, float e[8]) {
    const float xf0 = (float)xi.x, xf1 = (float)xi.y,
                xf2 = (float)xi.z, xf3 = (float)xi.w;
    const float Ct = lgam[xi.x] + lgam[xi.y] + lgam[xi.z] + lgam[xi.w];
#pragma unroll
    for (int r = 0; r < 8; ++r) {
      float a = -sumLam[r] - Ct;
      a = fmaf(xf0, Lt[r][0], a);
      a = fmaf(xf1, Lt[r][1], a);
      a = fmaf(xf2, Lt[r][2], a);
      a = fmaf(xf3, Lt[r][3], a);
      e[r] = a;
    }
  };

  if (chunk == 0) {
    // exact init from prior at t=0
    float lp0[8];
    {
      float m = logp0[0];
#pragma unroll
      for (int j = 1; j < 8; ++j) m = fmaxf(m, logp0[j]);
      float s = 0.f;
#pragma unroll
      for (int j = 0; j < 8; ++j) s += __expf(logp0[j] - m);
      float lg = m + __logf(s);
#pragma unroll
      for (int j = 0; j < 8; ++j) lp0[j] = logp0[j] - lg;
    }
    float lp1v, lp2v;
    {
      float m = logp1[0];
#pragma unroll
      for (int j = 1; j < 8; ++j) m = fmaxf(m, logp1[j]);
      float s = 0.f;
#pragma unroll
      for (int j = 0; j < 8; ++j) s += __expf(logp1[j] - m);
      lp1v = logp1[j1] - (m + __logf(s));
    }
    {
      float m = logp2[0];
#pragma unroll
      for (int j = 1; j < 8; ++j) m = fmaxf(m, logp2[j]);
      float s = 0.f;
#pragma unroll
      for (int j = 0; j < 8; ++j) s += __expf(logp2[j] - m);
      lp2v = logp2[j2] - (m + __logf(s));
    }
    float e[8];
    emis(*reinterpret_cast<const int4*>(x), e);
    float a[8];
    float mx = -3.0e38f;
#pragma unroll
    for (int r = 0; r < 8; ++r) {
      a[r] = lp0[r] + lp1v + lp2v + e[r];
      mx = fmaxf(mx, a[r]);
    }
    mx = wave_reduce_max(mx);
#pragma unroll
    for (int r = 0; r < 8; ++r) v[r] = __expf(a[r] - mx);
    zacc = (double)mx;
    t = 1;
  } else {
    // burn-in from a uniform (unnormalized) message
#pragma unroll
    for (int r = 0; r < 8; ++r) v[r] = 1.0f;
    t = tstart - BURN;
    if (t < 0) t = 0;
  }

  auto step = [&](int tt, bool accumulate) {
    const int4 xi = *reinterpret_cast<const int4*>(x + 4 * tt);
    float e[8];
    emis(xi, e);

    // ---- chain-0 contraction (in-lane over registers) ----
    float q[8];
#pragma unroll
    for (int j = 0; j < 8; ++j) {
      float a = T0f[j][0] * v[0];
#pragma unroll
      for (int k = 1; k < 8; ++k) a = fmaf(T0f[j][k], v[k], a);
      q[j] = a;
    }
    // ---- chain-1 contraction (cross-lane, lane bits 3..5) ----
#pragma unroll
    for (int j = 0; j < 8; ++j) {
      float a = 0.f;
#pragma unroll
      for (int k = 0; k < 8; ++k) {
        float g = __int_as_float(
            __builtin_amdgcn_ds_bpermute(a1[k], __float_as_int(q[j])));
        a = fmaf(T1r[k], g, a);
      }
      q[j] = a;
    }
    // ---- chain-2 contraction (cross-lane, lane bits 0..2) ----
#pragma unroll
    for (int j = 0; j < 8; ++j) {
      float a = 0.f;
#pragma unroll
      for (int k = 0; k < 8; ++k) {
        float g = __int_as_float(
            __builtin_amdgcn_ds_bpermute(a2[k], __float_as_int(q[j])));
        a = fmaf(T2r[k], g, a);
      }
      q[j] = a;
    }

    // ---- emission multiply with max-shift (range safety), then renormalize ----
    float me = e[0];
#pragma unroll
    for (int r = 1; r < 8; ++r) me = fmaxf(me, e[r]);
    me = wave_reduce_max(me);

    float c = 0.f;
#pragma unroll
    for (int r = 0; r < 8; ++r) {
      float tl = q[r] * __expf(e[r] - me);
      v[r] = tl;
      c = fmaxf(c, tl);
    }
    c = wave_reduce_max(c);
    const float rinv = __builtin_amdgcn_rcpf(c);
#pragma unroll
    for (int r = 0; r < 8; ++r) v[r] *= rinv;

    if (accumulate) zacc += (double)(__logf(c) + me);
  };

  for (; t < tstart; ++t) step(t, false);  // burn-in (discard normalizers)
  for (; t < tend; ++t) step(t, true);     // accumulate log c_t

  if (chunk == NCHUNK - 1) {
    float s = 0.f;
#pragma unroll
    for (int r = 0; r < 8; ++r) s += v[r];
    s = wave_reduce_sum(s);
    zacc += (double)__logf(s);
  }

  if (l == 0) atomicAdd(accum, zacc);
}

__global__ void zero_acc_kernel(double* acc) {
  if (threadIdx.x == 0) *acc = 0.0;
}
__global__ void finalize_kernel(const double* __restrict__ acc,
                                float* __restrict__ out) {
  if (threadIdx.x == 0) out[0] = (float)(*acc);
}

extern "C" void kernel_launch(void* const* d_in, const int* in_sizes, int n_in,
                              void* d_out, int out_size, void* d_ws, size_t ws_size,
                              hipStream_t stream) {
  const int*   x     = (const int*)d_in[0];
  const float* lam0  = (const float*)d_in[1];
  const float* lam1  = (const float*)d_in[2];
  const float* lam2  = (const float*)d_in[3];
  const float* logA0 = (const float*)d_in[4];
  const float* logA1 = (const float*)d_in[5];
  const float* logA2 = (const float*)d_in[6];
  const float* logp0 = (const float*)d_in[7];
  const float* logp1 = (const float*)d_in[8];
  const float* logp2 = (const float*)d_in[9];
  double* acc = (double*)d_ws;
  float*  out = (float*)d_out;

  zero_acc_kernel<<<1, 64, 0, stream>>>(acc);
  hmm_fwd_chunk<<<NCHUNK, 64, 0, stream>>>(x, lam0, lam1, lam2,
                                           logA0, logA1, logA2,
                                           logp0, logp1, logp2, acc);
  finalize_kernel<<<1, 64, 0, stream>>>(acc, out);
}

// Round 5
// 127.741 us; speedup vs baseline: 3.4676x; 1.3483x over previous
//
#include <hip/hip_runtime.h>

// Factorial HMM forward (3 chains x 8 states = 512 states, M=4, T=65536).
// Probability-domain scaled forward recurrence; transition applied as three
// 8x8 tensor contractions (chain-0 in-lane f32, chains 1/2 cross-lane via
// ds_bpermute of PACKED f16 pairs + v_pk_fma_f16). Chunked-parallel over T
// with burn-in. One wave per chunk; lane l=(j1,j2) holds states r*64+l.
// R3/R5: f16-packed exchange (128 -> 64 bpermutes/step), burst issue, addr
// arrays dropped. Messages are max-normalized to [0,1] each step, so f16
// relative error ~5e-4 -> O(10) nats total bias vs 6.6e4 threshold.
// R5 fixes R4's compile error: cvt_pkrtz returns __fp16x2, bit_cast to h2.

#define NCHUNK 4096
#define CLEN   16          // NCHUNK * CLEN == 65536
#define BURN   8

typedef _Float16 h2 __attribute__((ext_vector_type(2)));

static __device__ __forceinline__ int h2i(h2 v) { return __builtin_bit_cast(int, v); }
static __device__ __forceinline__ h2 ih2(int v) { return __builtin_bit_cast(h2, v); }
static __device__ __forceinline__ h2 pkrtz(float a, float b) {
  return __builtin_bit_cast(h2, __builtin_amdgcn_cvt_pkrtz(a, b));
}

__device__ __forceinline__ float wave_reduce_max(float v) {
#pragma unroll
  for (int m = 32; m >= 1; m >>= 1) v = fmaxf(v, __shfl_xor(v, m, 64));
  return v;
}
__device__ __forceinline__ float wave_reduce_sum(float v) {
#pragma unroll
  for (int m = 32; m >= 1; m >>= 1) v += __shfl_xor(v, m, 64);
  return v;
}

__global__ __launch_bounds__(64, 1)
void hmm_fwd_chunk(const int* __restrict__ x,
                   const float* __restrict__ lam0, const float* __restrict__ lam1,
                   const float* __restrict__ lam2,
                   const float* __restrict__ logA0, const float* __restrict__ logA1,
                   const float* __restrict__ logA2,
                   const float* __restrict__ logp0, const float* __restrict__ logp1,
                   const float* __restrict__ logp2,
                   double* __restrict__ accum)
{
  const int l = threadIdx.x;        // 0..63
  const int chunk = blockIdx.x;     // 0..NCHUNK-1
  const int j1 = l >> 3;            // chain-1 state of this lane
  const int j2 = l & 7;             // chain-2 state of this lane
  const int base1 = j2 << 2;        // chain-1 gather: addr = base1 + (k<<5)
  const int base2 = j1 << 5;        // chain-2 gather: addr = base2 + (k<<2)

  // log(n!) table for n = x in [0,19]  (lgamma(x+1))
  __shared__ float lgam[20];
  if (l == 0) {
    lgam[0]  = 0.0f;          lgam[1]  = 0.0f;
    lgam[2]  = 0.69314718f;   lgam[3]  = 1.79175947f;
    lgam[4]  = 3.17805383f;   lgam[5]  = 4.78749174f;
    lgam[6]  = 6.57925121f;   lgam[7]  = 8.52516136f;
    lgam[8]  = 10.60460290f;  lgam[9]  = 12.80182748f;
    lgam[10] = 15.10441257f;  lgam[11] = 17.50230785f;
    lgam[12] = 19.98721450f;  lgam[13] = 22.55216385f;
    lgam[14] = 25.19122118f;  lgam[15] = 27.89927138f;
    lgam[16] = 30.67186011f;  lgam[17] = 33.50507345f;
    lgam[18] = 36.39544521f;  lgam[19] = 39.33988419f;
  }
  __syncthreads();

  // ---- transition tables: T = exp(log_softmax(logA, axis=0)) ----
  // Chain 0: full 8x8 f32, lane-uniform (in-lane contraction).
  float T0f[8][8];
#pragma unroll
  for (int k = 0; k < 8; ++k) {
    float m = logA0[k];
#pragma unroll
    for (int j = 1; j < 8; ++j) m = fmaxf(m, logA0[j * 8 + k]);
    float s = 0.f;
#pragma unroll
    for (int j = 0; j < 8; ++j) s += __expf(logA0[j * 8 + k] - m);
    float inv = 1.0f / s;
#pragma unroll
    for (int j = 0; j < 8; ++j) T0f[j][k] = __expf(logA0[j * 8 + k] - m) * inv;
  }
  // Chain 1: lane keeps row T1[j1, k], duplicated into an f16 pair.
  h2 T1h[8];
#pragma unroll
  for (int k = 0; k < 8; ++k) {
    float m = logA1[k];
#pragma unroll
    for (int j = 1; j < 8; ++j) m = fmaxf(m, logA1[j * 8 + k]);
    float s = 0.f;
#pragma unroll
    for (int j = 0; j < 8; ++j) s += __expf(logA1[j * 8 + k] - m);
    float t = __expf(logA1[j1 * 8 + k] - m) / s;
    T1h[k] = pkrtz(t, t);
  }
  // Chain 2: lane keeps row T2[j2, k], duplicated into an f16 pair.
  h2 T2h[8];
#pragma unroll
  for (int k = 0; k < 8; ++k) {
    float m = logA2[k];
#pragma unroll
    for (int j = 1; j < 8; ++j) m = fmaxf(m, logA2[j * 8 + k]);
    float s = 0.f;
#pragma unroll
    for (int j = 0; j < 8; ++j) s += __expf(logA2[j * 8 + k] - m);
    float t = __expf(logA2[j2 * 8 + k] - m) / s;
    T2h[k] = pkrtz(t, t);
  }

  // ---- emission tables: log(lambdaC) and sum(lambdaC) for lane's 8 states ----
  float Lt[8][4], sumLam[8];
#pragma unroll
  for (int r = 0; r < 8; ++r) {
    float s = 0.f;
#pragma unroll
    for (int m = 0; m < 4; ++m) {
      float lam = lam0[r * 4 + m] + lam1[j1 * 4 + m] + lam2[j2 * 4 + m];
      Lt[r][m] = __logf(lam);
      s += lam;
    }
    sumLam[r] = s;
  }

  const int tstart = chunk * CLEN;
  const int tend = tstart + CLEN;

  float v[8];
  double zacc = 0.0;
  int t;

  // emission log-prob (incl. -C_t) for all 8 register states
  auto emis = [&](const int4 xi, float e[8]) {
    const float xf0 = (float)xi.x, xf1 = (float)xi.y,
                xf2 = (float)xi.z, xf3 = (float)xi.w;
    const float Ct = lgam[xi.x] + lgam[xi.y] + lgam[xi.z] + lgam[xi.w];
#pragma unroll
    for (int r = 0; r < 8; ++r) {
      float a = -sumLam[r] - Ct;
      a = fmaf(xf0, Lt[r][0], a);
      a = fmaf(xf1, Lt[r][1], a);
      a = fmaf(xf2, Lt[r][2], a);
      a = fmaf(xf3, Lt[r][3], a);
      e[r] = a;
    }
  };

  if (chunk == 0) {
    // exact init from prior at t=0
    float lp0[8];
    {
      float m = logp0[0];
#pragma unroll
      for (int j = 1; j < 8; ++j) m = fmaxf(m, logp0[j]);
      float s = 0.f;
#pragma unroll
      for (int j = 0; j < 8; ++j) s += __expf(logp0[j] - m);
      float lg = m + __logf(s);
#pragma unroll
      for (int j = 0; j < 8; ++j) lp0[j] = logp0[j] - lg;
    }
    float lp1v, lp2v;
    {
      float m = logp1[0];
#pragma unroll
      for (int j = 1; j < 8; ++j) m = fmaxf(m, logp1[j]);
      float s = 0.f;
#pragma unroll
      for (int j = 0; j < 8; ++j) s += __expf(logp1[j] - m);
      lp1v = logp1[j1] - (m + __logf(s));
    }
    {
      float m = logp2[0];
#pragma unroll
      for (int j = 1; j < 8; ++j) m = fmaxf(m, logp2[j]);
      float s = 0.f;
#pragma unroll
      for (int j = 0; j < 8; ++j) s += __expf(logp2[j] - m);
      lp2v = logp2[j2] - (m + __logf(s));
    }
    float e[8];
    emis(*reinterpret_cast<const int4*>(x), e);
    float a[8];
    float mx = -3.0e38f;
#pragma unroll
    for (int r = 0; r < 8; ++r) {
      a[r] = lp0[r] + lp1v + lp2v + e[r];
      mx = fmaxf(mx, a[r]);
    }
    mx = wave_reduce_max(mx);
#pragma unroll
    for (int r = 0; r < 8; ++r) v[r] = __expf(a[r] - mx);
    zacc = (double)mx;
    t = 1;
  } else {
    // burn-in from a uniform (unnormalized) message
#pragma unroll
    for (int r = 0; r < 8; ++r) v[r] = 1.0f;
    t = tstart - BURN;
    if (t < 0) t = 0;
  }

  auto step = [&](int tt, bool accumulate) {
    const int4 xi = *reinterpret_cast<const int4*>(x + 4 * tt);
    float e[8];
    emis(xi, e);

    // ---- chain-0 contraction (in-lane f32 over registers) ----
    float q[8];
#pragma unroll
    for (int j = 0; j < 8; ++j) {
      float a = T0f[j][0] * v[0];
#pragma unroll
      for (int k = 1; k < 8; ++k) a = fmaf(T0f[j][k], v[k], a);
      q[j] = a;
    }

    // ---- pack r-pairs to f16x2 ----
    int qp[4];
#pragma unroll
    for (int p = 0; p < 4; ++p)
      qp[p] = h2i(pkrtz(q[2 * p], q[2 * p + 1]));

    // ---- chain-1 contraction (cross-lane, lane bits 3..5), packed ----
    // out_r = sum_k T1[j1,k] * q_r(lane (k, j2));  addr = (k<<5) + (j2<<2)
    h2 acc1[4];
#pragma unroll
    for (int p = 0; p < 4; ++p) acc1[p] = h2{(_Float16)0.f, (_Float16)0.f};
#pragma unroll
    for (int half = 0; half < 2; ++half) {
      int g[2][8];
#pragma unroll
      for (int p = 0; p < 2; ++p)
#pragma unroll
        for (int k = 0; k < 8; ++k)
          g[p][k] = __builtin_amdgcn_ds_bpermute(base1 + (k << 5),
                                                 qp[half * 2 + p]);
#pragma unroll
      for (int p = 0; p < 2; ++p)
#pragma unroll
        for (int k = 0; k < 8; ++k)
          acc1[half * 2 + p] += T1h[k] * ih2(g[p][k]);
    }

    // ---- chain-2 contraction (cross-lane, lane bits 0..2), packed ----
    // out_r = sum_k T2[j2,k] * in_r(lane (j1, k));  addr = (j1<<5) + (k<<2)
    int q2p[4];
#pragma unroll
    for (int p = 0; p < 4; ++p) q2p[p] = h2i(acc1[p]);
    h2 acc2[4];
#pragma unroll
    for (int p = 0; p < 4; ++p) acc2[p] = h2{(_Float16)0.f, (_Float16)0.f};
#pragma unroll
    for (int half = 0; half < 2; ++half) {
      int g[2][8];
#pragma unroll
      for (int p = 0; p < 2; ++p)
#pragma unroll
        for (int k = 0; k < 8; ++k)
          g[p][k] = __builtin_amdgcn_ds_bpermute(base2 + (k << 2),
                                                 q2p[half * 2 + p]);
#pragma unroll
      for (int p = 0; p < 2; ++p)
#pragma unroll
        for (int k = 0; k < 8; ++k)
          acc2[half * 2 + p] += T2h[k] * ih2(g[p][k]);
    }

    // ---- unpack ----
    float w[8];
#pragma unroll
    for (int p = 0; p < 4; ++p) {
      w[2 * p]     = (float)acc2[p].x;
      w[2 * p + 1] = (float)acc2[p].y;
    }

    // ---- emission multiply with max-shift, then renormalize ----
    float me = e[0];
#pragma unroll
    for (int r = 1; r < 8; ++r) me = fmaxf(me, e[r]);
    me = wave_reduce_max(me);

    float c = 0.f;
#pragma unroll
    for (int r = 0; r < 8; ++r) {
      float tl = w[r] * __expf(e[r] - me);
      v[r] = tl;
      c = fmaxf(c, tl);
    }
    c = wave_reduce_max(c);
    const float rinv = __builtin_amdgcn_rcpf(c);
#pragma unroll
    for (int r = 0; r < 8; ++r) v[r] *= rinv;

    if (accumulate) zacc += (double)(__logf(c) + me);
  };

  for (; t < tstart; ++t) step(t, false);  // burn-in (discard normalizers)
  for (; t < tend; ++t) step(t, true);     // accumulate log c_t

  if (chunk == NCHUNK - 1) {
    float s = 0.f;
#pragma unroll
    for (int r = 0; r < 8; ++r) s += v[r];
    s = wave_reduce_sum(s);
    zacc += (double)__logf(s);
  }

  if (l == 0) atomicAdd(accum, zacc);
}

__global__ void zero_acc_kernel(double* acc) {
  if (threadIdx.x == 0) *acc = 0.0;
}
__global__ void finalize_kernel(const double* __restrict__ acc,
                                float* __restrict__ out) {
  if (threadIdx.x == 0) out[0] = (float)(*acc);
}

extern "C" void kernel_launch(void* const* d_in, const int* in_sizes, int n_in,
                              void* d_out, int out_size, void* d_ws, size_t ws_size,
                              hipStream_t stream) {
  const int*   x     = (const int*)d_in[0];
  const float* lam0  = (const float*)d_in[1];
  const float* lam1  = (const float*)d_in[2];
  const float* lam2  = (const float*)d_in[3];
  const float* logA0 = (const float*)d_in[4];
  const float* logA1 = (const float*)d_in[5];
  const float* logA2 = (const float*)d_in[6];
  const float* logp0 = (const float*)d_in[7];
  const float* logp1 = (const float*)d_in[8];
  const float* logp2 = (const float*)d_in[9];
  double* acc = (double*)d_ws;
  float*  out = (float*)d_out;

  zero_acc_kernel<<<1, 64, 0, stream>>>(acc);
  hmm_fwd_chunk<<<NCHUNK, 64, 0, stream>>>(x, lam0, lam1, lam2,
                                           logA0, logA1, logA2,
                                           logp0, logp1, logp2, acc);
  finalize_kernel<<<1, 64, 0, stream>>>(acc, out);
}

// Round 6
// 122.137 us; speedup vs baseline: 3.6267x; 1.0459x over previous
//
#include <hip/hip_runtime.h>

// Factorial HMM forward (3 chains x 8 states = 512 states, M=4, T=65536).
// Probability-domain scaled forward recurrence; transition = three 8x8
// contractions (chain-0 in-lane f32, chains 1/2 cross-lane ds_bpermute of
// packed f16 pairs + v_pk_fma_f16). Chunk-parallel over T with burn-in.
// One wave per chunk; lane l=(j1,j2) holds states r*64+l.
// R6: (1) wave-max reduces via DPP (VALU) instead of __shfl_xor (DS pipe) --
// exact same max, ~25cy vs ~650cy; (2) x prefetched one step ahead;
// (3) 4 chunks per 256-thread block, launch_bounds(256,1) (register budget
// unchanged -- R1's regression was the min-waves=4 arg, not block size).

#define NCHUNK 4096
#define CLEN   16          // NCHUNK * CLEN == 65536
#define BURN   8

typedef _Float16 h2 __attribute__((ext_vector_type(2)));

static __device__ __forceinline__ int h2i(h2 v) { return __builtin_bit_cast(int, v); }
static __device__ __forceinline__ h2 ih2(int v) { return __builtin_bit_cast(h2, v); }
static __device__ __forceinline__ h2 pkrtz(float a, float b) {
  return __builtin_bit_cast(h2, __builtin_amdgcn_cvt_pkrtz(a, b));
}

// Wave(64)-wide max via DPP butterfly on the VALU pipe (no DS ops).
// row_shr 1/2/4/8 accumulate row maxes into lane 15 of each 16-lane row;
// row_bcast:15 / row_bcast:31 cross the 16/32 boundaries; lane 63 ends with
// the full max, broadcast via readlane. Invalid-lane DPP reads keep `old`
// (=accumulator), so negative inputs are handled exactly.
static __device__ __forceinline__ float wave_max_dpp(float x) {
  int r = __builtin_bit_cast(int, x);
  auto mx = [](int a, int b) {
    return __builtin_bit_cast(
        int, fmaxf(__builtin_bit_cast(float, a), __builtin_bit_cast(float, b)));
  };
  int t;
  t = __builtin_amdgcn_update_dpp(r, r, 0x111, 0xf, 0xf, false); r = mx(r, t);
  t = __builtin_amdgcn_update_dpp(r, r, 0x112, 0xf, 0xf, false); r = mx(r, t);
  t = __builtin_amdgcn_update_dpp(r, r, 0x114, 0xf, 0xf, false); r = mx(r, t);
  t = __builtin_amdgcn_update_dpp(r, r, 0x118, 0xf, 0xf, false); r = mx(r, t);
  t = __builtin_amdgcn_update_dpp(r, r, 0x142, 0xa, 0xf, false); r = mx(r, t);
  t = __builtin_amdgcn_update_dpp(r, r, 0x143, 0xc, 0xf, false); r = mx(r, t);
  return __builtin_bit_cast(float, __builtin_amdgcn_readlane(r, 63));
}

__device__ __forceinline__ float wave_reduce_sum(float v) {
#pragma unroll
  for (int m = 32; m >= 1; m >>= 1) v += __shfl_xor(v, m, 64);
  return v;
}

__global__ __launch_bounds__(256, 1)
void hmm_fwd_chunk(const int* __restrict__ x,
                   const float* __restrict__ lam0, const float* __restrict__ lam1,
                   const float* __restrict__ lam2,
                   const float* __restrict__ logA0, const float* __restrict__ logA1,
                   const float* __restrict__ logA2,
                   const float* __restrict__ logp0, const float* __restrict__ logp1,
                   const float* __restrict__ logp2,
                   double* __restrict__ accum)
{
  const int l = threadIdx.x & 63;                          // lane 0..63
  const int chunk = blockIdx.x * 4 + (threadIdx.x >> 6);   // 0..NCHUNK-1
  const int j1 = l >> 3;            // chain-1 state of this lane
  const int j2 = l & 7;             // chain-2 state of this lane
  const int base1 = j2 << 2;        // chain-1 gather: addr = base1 + (k<<5)
  const int base2 = j1 << 5;        // chain-2 gather: addr = base2 + (k<<2)

  // log(n!) table for n = x in [0,19]  (lgamma(x+1))
  __shared__ float lgam[20];
  if (threadIdx.x == 0) {
    lgam[0]  = 0.0f;          lgam[1]  = 0.0f;
    lgam[2]  = 0.69314718f;   lgam[3]  = 1.79175947f;
    lgam[4]  = 3.17805383f;   lgam[5]  = 4.78749174f;
    lgam[6]  = 6.57925121f;   lgam[7]  = 8.52516136f;
    lgam[8]  = 10.60460290f;  lgam[9]  = 12.80182748f;
    lgam[10] = 15.10441257f;  lgam[11] = 17.50230785f;
    lgam[12] = 19.98721450f;  lgam[13] = 22.55216385f;
    lgam[14] = 25.19122118f;  lgam[15] = 27.89927138f;
    lgam[16] = 30.67186011f;  lgam[17] = 33.50507345f;
    lgam[18] = 36.39544521f;  lgam[19] = 39.33988419f;
  }
  __syncthreads();

  // ---- transition tables: T = exp(log_softmax(logA, axis=0)) ----
  // Chain 0: full 8x8 f32, lane-uniform (in-lane contraction).
  float T0f[8][8];
#pragma unroll
  for (int k = 0; k < 8; ++k) {
    float m = logA0[k];
#pragma unroll
    for (int j = 1; j < 8; ++j) m = fmaxf(m, logA0[j * 8 + k]);
    float s = 0.f;
#pragma unroll
    for (int j = 0; j < 8; ++j) s += __expf(logA0[j * 8 + k] - m);
    float inv = 1.0f / s;
#pragma unroll
    for (int j = 0; j < 8; ++j) T0f[j][k] = __expf(logA0[j * 8 + k] - m) * inv;
  }
  // Chain 1: lane keeps row T1[j1, k], duplicated into an f16 pair.
  h2 T1h[8];
#pragma unroll
  for (int k = 0; k < 8; ++k) {
    float m = logA1[k];
#pragma unroll
    for (int j = 1; j < 8; ++j) m = fmaxf(m, logA1[j * 8 + k]);
    float s = 0.f;
#pragma unroll
    for (int j = 0; j < 8; ++j) s += __expf(logA1[j * 8 + k] - m);
    float t = __expf(logA1[j1 * 8 + k] - m) / s;
    T1h[k] = pkrtz(t, t);
  }
  // Chain 2: lane keeps row T2[j2, k], duplicated into an f16 pair.
  h2 T2h[8];
#pragma unroll
  for (int k = 0; k < 8; ++k) {
    float m = logA2[k];
#pragma unroll
    for (int j = 1; j < 8; ++j) m = fmaxf(m, logA2[j * 8 + k]);
    float s = 0.f;
#pragma unroll
    for (int j = 0; j < 8; ++j) s += __expf(logA2[j * 8 + k] - m);
    float t = __expf(logA2[j2 * 8 + k] - m) / s;
    T2h[k] = pkrtz(t, t);
  }

  // ---- emission tables: log(lambdaC) and sum(lambdaC) for lane's 8 states ----
  float Lt[8][4], sumLam[8];
#pragma unroll
  for (int r = 0; r < 8; ++r) {
    float s = 0.f;
#pragma unroll
    for (int m = 0; m < 4; ++m) {
      float lam = lam0[r * 4 + m] + lam1[j1 * 4 + m] + lam2[j2 * 4 + m];
      Lt[r][m] = __logf(lam);
      s += lam;
    }
    sumLam[r] = s;
  }

  const int tstart = chunk * CLEN;
  const int tend = tstart + CLEN;

  float v[8];
  double zacc = 0.0;
  int t0;

  // emission log-prob (incl. -C_t) for all 8 register states
  auto emis = [&](const int4 xi, float e[8]) {
    const float xf0 = (float)xi.x, xf1 = (float)xi.y,
                xf2 = (float)xi.z, xf3 = (float)xi.w;
    const float Ct = lgam[xi.x] + lgam[xi.y] + lgam[xi.z] + lgam[xi.w];
#pragma unroll
    for (int r = 0; r < 8; ++r) {
      float a = -sumLam[r] - Ct;
      a = fmaf(xf0, Lt[r][0], a);
      a = fmaf(xf1, Lt[r][1], a);
      a = fmaf(xf2, Lt[r][2], a);
      a = fmaf(xf3, Lt[r][3], a);
      e[r] = a;
    }
  };

  if (chunk == 0) {
    // exact init from prior at t=0
    float lp0[8];
    {
      float m = logp0[0];
#pragma unroll
      for (int j = 1; j < 8; ++j) m = fmaxf(m, logp0[j]);
      float s = 0.f;
#pragma unroll
      for (int j = 0; j < 8; ++j) s += __expf(logp0[j] - m);
      float lg = m + __logf(s);
#pragma unroll
      for (int j = 0; j < 8; ++j) lp0[j] = logp0[j] - lg;
    }
    float lp1v, lp2v;
    {
      float m = logp1[0];
#pragma unroll
      for (int j = 1; j < 8; ++j) m = fmaxf(m, logp1[j]);
      float s = 0.f;
#pragma unroll
      for (int j = 0; j < 8; ++j) s += __expf(logp1[j] - m);
      lp1v = logp1[j1] - (m + __logf(s));
    }
    {
      float m = logp2[0];
#pragma unroll
      for (int j = 1; j < 8; ++j) m = fmaxf(m, logp2[j]);
      float s = 0.f;
#pragma unroll
      for (int j = 0; j < 8; ++j) s += __expf(logp2[j] - m);
      lp2v = logp2[j2] - (m + __logf(s));
    }
    float e[8];
    emis(*reinterpret_cast<const int4*>(x), e);
    float a[8];
    float mx = -3.0e38f;
#pragma unroll
    for (int r = 0; r < 8; ++r) {
      a[r] = lp0[r] + lp1v + lp2v + e[r];
      mx = fmaxf(mx, a[r]);
    }
    mx = wave_max_dpp(mx);
#pragma unroll
    for (int r = 0; r < 8; ++r) v[r] = __expf(a[r] - mx);
    zacc = (double)mx;
    t0 = 1;
  } else {
    // burn-in from a uniform (unnormalized) message
#pragma unroll
    for (int r = 0; r < 8; ++r) v[r] = 1.0f;
    t0 = tstart - BURN;
  }

  // merged burn-in + accumulate loop, x prefetched one step ahead
  int4 xi_next = *reinterpret_cast<const int4*>(x + 4 * t0);
  for (int t = t0; t < tend; ++t) {
    const int4 xi = xi_next;
    if (t + 1 < tend)
      xi_next = *reinterpret_cast<const int4*>(x + 4 * (t + 1));

    float e[8];
    emis(xi, e);

    // ---- chain-0 contraction (in-lane f32 over registers) ----
    float q[8];
#pragma unroll
    for (int j = 0; j < 8; ++j) {
      float a = T0f[j][0] * v[0];
#pragma unroll
      for (int k = 1; k < 8; ++k) a = fmaf(T0f[j][k], v[k], a);
      q[j] = a;
    }

    // ---- pack r-pairs to f16x2 ----
    int qp[4];
#pragma unroll
    for (int p = 0; p < 4; ++p)
      qp[p] = h2i(pkrtz(q[2 * p], q[2 * p + 1]));

    // ---- chain-1 contraction (cross-lane, lane bits 3..5), packed ----
    // out_r = sum_k T1[j1,k] * q_r(lane (k, j2));  addr = (k<<5) + (j2<<2)
    h2 acc1[4];
#pragma unroll
    for (int p = 0; p < 4; ++p) acc1[p] = h2{(_Float16)0.f, (_Float16)0.f};
#pragma unroll
    for (int half = 0; half < 2; ++half) {
      int g[2][8];
#pragma unroll
      for (int p = 0; p < 2; ++p)
#pragma unroll
        for (int k = 0; k < 8; ++k)
          g[p][k] = __builtin_amdgcn_ds_bpermute(base1 + (k << 5),
                                                 qp[half * 2 + p]);
#pragma unroll
      for (int p = 0; p < 2; ++p)
#pragma unroll
        for (int k = 0; k < 8; ++k)
          acc1[half * 2 + p] += T1h[k] * ih2(g[p][k]);
    }

    // ---- chain-2 contraction (cross-lane, lane bits 0..2), packed ----
    // out_r = sum_k T2[j2,k] * in_r(lane (j1, k));  addr = (j1<<5) + (k<<2)
    int q2p[4];
#pragma unroll
    for (int p = 0; p < 4; ++p) q2p[p] = h2i(acc1[p]);
    h2 acc2[4];
#pragma unroll
    for (int p = 0; p < 4; ++p) acc2[p] = h2{(_Float16)0.f, (_Float16)0.f};
#pragma unroll
    for (int half = 0; half < 2; ++half) {
      int g[2][8];
#pragma unroll
      for (int p = 0; p < 2; ++p)
#pragma unroll
        for (int k = 0; k < 8; ++k)
          g[p][k] = __builtin_amdgcn_ds_bpermute(base2 + (k << 2),
                                                 q2p[half * 2 + p]);
#pragma unroll
      for (int p = 0; p < 2; ++p)
#pragma unroll
        for (int k = 0; k < 8; ++k)
          acc2[half * 2 + p] += T2h[k] * ih2(g[p][k]);
    }

    // ---- unpack ----
    float w[8];
#pragma unroll
    for (int p = 0; p < 4; ++p) {
      w[2 * p]     = (float)acc2[p].x;
      w[2 * p + 1] = (float)acc2[p].y;
    }

    // ---- emission multiply with max-shift, then renormalize ----
    float me = e[0];
#pragma unroll
    for (int r = 1; r < 8; ++r) me = fmaxf(me, e[r]);
    me = wave_max_dpp(me);

    float c = 0.f;
#pragma unroll
    for (int r = 0; r < 8; ++r) {
      float tl = w[r] * __expf(e[r] - me);
      v[r] = tl;
      c = fmaxf(c, tl);
    }
    c = wave_max_dpp(c);
    const float rinv = __builtin_amdgcn_rcpf(c);
#pragma unroll
    for (int r = 0; r < 8; ++r) v[r] *= rinv;

    if (t >= tstart) zacc += (double)(__logf(c) + me);
  }

  if (chunk == NCHUNK - 1) {
    float s = 0.f;
#pragma unroll
    for (int r = 0; r < 8; ++r) s += v[r];
    s = wave_reduce_sum(s);
    zacc += (double)__logf(s);
  }

  if (l == 0) atomicAdd(accum, zacc);
}

__global__ void zero_acc_kernel(double* acc) {
  if (threadIdx.x == 0) *acc = 0.0;
}
__global__ void finalize_kernel(const double* __restrict__ acc,
                                float* __restrict__ out) {
  if (threadIdx.x == 0) out[0] = (float)(*acc);
}

extern "C" void kernel_launch(void* const* d_in, const int* in_sizes, int n_in,
                              void* d_out, int out_size, void* d_ws, size_t ws_size,
                              hipStream_t stream) {
  const int*   x     = (const int*)d_in[0];
  const float* lam0  = (const float*)d_in[1];
  const float* lam1  = (const float*)d_in[2];
  const float* lam2  = (const float*)d_in[3];
  const float* logA0 = (const float*)d_in[4];
  const float* logA1 = (const float*)d_in[5];
  const float* logA2 = (const float*)d_in[6];
  const float* logp0 = (const float*)d_in[7];
  const float* logp1 = (const float*)d_in[8];
  const float* logp2 = (const float*)d_in[9];
  double* acc = (double*)d_ws;
  float*  out = (float*)d_out;

  zero_acc_kernel<<<1, 64, 0, stream>>>(acc);
  hmm_fwd_chunk<<<NCHUNK / 4, 256, 0, stream>>>(x, lam0, lam1, lam2,
                                                logA0, logA1, logA2,
                                                logp0, logp1, logp2, acc);
  finalize_kernel<<<1, 64, 0, stream>>>(acc, out);
}

// Round 7
// 87.471 us; speedup vs baseline: 5.0640x; 1.3963x over previous
//
#include <hip/hip_runtime.h>

// Factorial HMM forward (3 chains x 8 states = 512 states, M=4, T=65536).
// Probability-domain scaled forward recurrence; transition = three 8x8
// contractions: chain-0 in-lane f32; chains 1/2 via LDS-staged f16-packed
// exchange (1 ds_write_b128 + 8 ds_read_b128 each) + v_pk_fma_f16.
// Chunk-parallel over T with burn-in. Lane l=(j1,j2) holds states r*64+l.
// R7: (1) bpermute exchange (64 DS ops, ~4600cy exposed latency/step) ->
// LDS b128 exchange (18 DS ops); (2) wave-uniform lgamma term Ct moved off
// the critical path (cancels in exp(e-me); side-accumulated); (3) BURN 8->4.

#define NCHUNK 4096
#define CLEN   16          // NCHUNK * CLEN == 65536
#define BURN   4

typedef _Float16 h2 __attribute__((ext_vector_type(2)));

static __device__ __forceinline__ int h2i(h2 v) { return __builtin_bit_cast(int, v); }
static __device__ __forceinline__ h2 ih2(int v) { return __builtin_bit_cast(h2, v); }
static __device__ __forceinline__ h2 pkrtz(float a, float b) {
  return __builtin_bit_cast(h2, __builtin_amdgcn_cvt_pkrtz(a, b));
}

// Wave(64)-wide max via DPP butterfly on the VALU pipe (no DS ops).
static __device__ __forceinline__ float wave_max_dpp(float x) {
  int r = __builtin_bit_cast(int, x);
  auto mx = [](int a, int b) {
    return __builtin_bit_cast(
        int, fmaxf(__builtin_bit_cast(float, a), __builtin_bit_cast(float, b)));
  };
  int t;
  t = __builtin_amdgcn_update_dpp(r, r, 0x111, 0xf, 0xf, false); r = mx(r, t);
  t = __builtin_amdgcn_update_dpp(r, r, 0x112, 0xf, 0xf, false); r = mx(r, t);
  t = __builtin_amdgcn_update_dpp(r, r, 0x114, 0xf, 0xf, false); r = mx(r, t);
  t = __builtin_amdgcn_update_dpp(r, r, 0x118, 0xf, 0xf, false); r = mx(r, t);
  t = __builtin_amdgcn_update_dpp(r, r, 0x142, 0xa, 0xf, false); r = mx(r, t);
  t = __builtin_amdgcn_update_dpp(r, r, 0x143, 0xc, 0xf, false); r = mx(r, t);
  return __builtin_bit_cast(float, __builtin_amdgcn_readlane(r, 63));
}

__device__ __forceinline__ float wave_reduce_sum(float v) {
#pragma unroll
  for (int m = 32; m >= 1; m >>= 1) v += __shfl_xor(v, m, 64);
  return v;
}

__global__ __launch_bounds__(256, 1)
void hmm_fwd_chunk(const int* __restrict__ x,
                   const float* __restrict__ lam0, const float* __restrict__ lam1,
                   const float* __restrict__ lam2,
                   const float* __restrict__ logA0, const float* __restrict__ logA1,
                   const float* __restrict__ logA2,
                   const float* __restrict__ logp0, const float* __restrict__ logp1,
                   const float* __restrict__ logp2,
                   double* __restrict__ accum)
{
  const int l = threadIdx.x & 63;                          // lane 0..63
  const int w = threadIdx.x >> 6;                          // wave-in-block 0..3
  const int chunk = blockIdx.x * 4 + w;                    // 0..NCHUNK-1
  const int j1 = l >> 3;            // chain-1 state of this lane
  const int j2 = l & 7;             // chain-2 state of this lane

  // log(n!) table for n = x in [0,19]  (lgamma(x+1))
  __shared__ float lgam[20];
  // per-wave exchange buffers: [buf][wave][row(k-major)] of 16B
  __shared__ int4 exA[4][64];
  __shared__ int4 exB[4][64];
  if (threadIdx.x == 0) {
    lgam[0]  = 0.0f;          lgam[1]  = 0.0f;
    lgam[2]  = 0.69314718f;   lgam[3]  = 1.79175947f;
    lgam[4]  = 3.17805383f;   lgam[5]  = 4.78749174f;
    lgam[6]  = 6.57925121f;   lgam[7]  = 8.52516136f;
    lgam[8]  = 10.60460290f;  lgam[9]  = 12.80182748f;
    lgam[10] = 15.10441257f;  lgam[11] = 17.50230785f;
    lgam[12] = 19.98721450f;  lgam[13] = 22.55216385f;
    lgam[14] = 25.19122118f;  lgam[15] = 27.89927138f;
    lgam[16] = 30.67186011f;  lgam[17] = 33.50507345f;
    lgam[18] = 36.39544521f;  lgam[19] = 39.33988419f;
  }
  __syncthreads();

  // ---- transition tables: T = exp(log_softmax(logA, axis=0)) ----
  // Chain 0: full 8x8 f32, lane-uniform (in-lane contraction).
  float T0f[8][8];
#pragma unroll
  for (int k = 0; k < 8; ++k) {
    float m = logA0[k];
#pragma unroll
    for (int j = 1; j < 8; ++j) m = fmaxf(m, logA0[j * 8 + k]);
    float s = 0.f;
#pragma unroll
    for (int j = 0; j < 8; ++j) s += __expf(logA0[j * 8 + k] - m);
    float inv = 1.0f / s;
#pragma unroll
    for (int j = 0; j < 8; ++j) T0f[j][k] = __expf(logA0[j * 8 + k] - m) * inv;
  }
  // Chain 1: lane keeps row T1[j1, k], duplicated into an f16 pair.
  h2 T1h[8];
#pragma unroll
  for (int k = 0; k < 8; ++k) {
    float m = logA1[k];
#pragma unroll
    for (int j = 1; j < 8; ++j) m = fmaxf(m, logA1[j * 8 + k]);
    float s = 0.f;
#pragma unroll
    for (int j = 0; j < 8; ++j) s += __expf(logA1[j * 8 + k] - m);
    float t = __expf(logA1[j1 * 8 + k] - m) / s;
    T1h[k] = pkrtz(t, t);
  }
  // Chain 2: lane keeps row T2[j2, k], duplicated into an f16 pair.
  h2 T2h[8];
#pragma unroll
  for (int k = 0; k < 8; ++k) {
    float m = logA2[k];
#pragma unroll
    for (int j = 1; j < 8; ++j) m = fmaxf(m, logA2[j * 8 + k]);
    float s = 0.f;
#pragma unroll
    for (int j = 0; j < 8; ++j) s += __expf(logA2[j * 8 + k] - m);
    float t = __expf(logA2[j2 * 8 + k] - m) / s;
    T2h[k] = pkrtz(t, t);
  }

  // ---- emission tables: log(lambdaC) and sum(lambdaC) for lane's 8 states ----
  float Lt[8][4], sumLam[8];
#pragma unroll
  for (int r = 0; r < 8; ++r) {
    float s = 0.f;
#pragma unroll
    for (int m = 0; m < 4; ++m) {
      float lam = lam0[r * 4 + m] + lam1[j1 * 4 + m] + lam2[j2 * 4 + m];
      Lt[r][m] = __logf(lam);
      s += lam;
    }
    sumLam[r] = s;
  }

  const int tstart = chunk * CLEN;
  const int tend = tstart + CLEN;

  float v[8];
  double zacc = 0.0;
  float ctsum = 0.f;   // sum of wave-uniform lgamma terms over accumulated steps
  int t0;

  // emission log-prob EXCLUDING the wave-uniform -Ct term
  auto emis = [&](const int4 xi, float e[8]) {
    const float xf0 = (float)xi.x, xf1 = (float)xi.y,
                xf2 = (float)xi.z, xf3 = (float)xi.w;
#pragma unroll
    for (int r = 0; r < 8; ++r) {
      float a = -sumLam[r];
      a = fmaf(xf0, Lt[r][0], a);
      a = fmaf(xf1, Lt[r][1], a);
      a = fmaf(xf2, Lt[r][2], a);
      a = fmaf(xf3, Lt[r][3], a);
      e[r] = a;
    }
  };

  if (chunk == 0) {
    // exact init from prior at t=0
    float lp0[8];
    {
      float m = logp0[0];
#pragma unroll
      for (int j = 1; j < 8; ++j) m = fmaxf(m, logp0[j]);
      float s = 0.f;
#pragma unroll
      for (int j = 0; j < 8; ++j) s += __expf(logp0[j] - m);
      float lg = m + __logf(s);
#pragma unroll
      for (int j = 0; j < 8; ++j) lp0[j] = logp0[j] - lg;
    }
    float lp1v, lp2v;
    {
      float m = logp1[0];
#pragma unroll
      for (int j = 1; j < 8; ++j) m = fmaxf(m, logp1[j]);
      float s = 0.f;
#pragma unroll
      for (int j = 0; j < 8; ++j) s += __expf(logp1[j] - m);
      lp1v = logp1[j1] - (m + __logf(s));
    }
    {
      float m = logp2[0];
#pragma unroll
      for (int j = 1; j < 8; ++j) m = fmaxf(m, logp2[j]);
      float s = 0.f;
#pragma unroll
      for (int j = 0; j < 8; ++j) s += __expf(logp2[j] - m);
      lp2v = logp2[j2] - (m + __logf(s));
    }
    const int4 xi0 = *reinterpret_cast<const int4*>(x);
    float e[8];
    emis(xi0, e);
    ctsum = lgam[xi0.x] + lgam[xi0.y] + lgam[xi0.z] + lgam[xi0.w];
    float a[8];
    float mxl = -3.0e38f;
#pragma unroll
    for (int r = 0; r < 8; ++r) {
      a[r] = lp0[r] + lp1v + lp2v + e[r];
      mxl = fmaxf(mxl, a[r]);
    }
    mxl = wave_max_dpp(mxl);
#pragma unroll
    for (int r = 0; r < 8; ++r) v[r] = __expf(a[r] - mxl);
    zacc = (double)mxl;
    t0 = 1;
  } else {
    // burn-in from a uniform (unnormalized) message
#pragma unroll
    for (int r = 0; r < 8; ++r) v[r] = 1.0f;
    t0 = tstart - BURN;
  }

  // merged burn-in + accumulate loop, x prefetched one step ahead
  int4 xi_next = *reinterpret_cast<const int4*>(x + 4 * t0);
  for (int t = t0; t < tend; ++t) {
    const int4 xi = xi_next;
    if (t + 1 < tend)
      xi_next = *reinterpret_cast<const int4*>(x + 4 * (t + 1));

    // emission (no Ct) and its wave max -- independent of v, overlaps mixing
    float e[8];
    emis(xi, e);
    float me = e[0];
#pragma unroll
    for (int r = 1; r < 8; ++r) me = fmaxf(me, e[r]);
    me = wave_max_dpp(me);

    // ---- chain-0 contraction (in-lane f32 over registers) ----
    float q[8];
#pragma unroll
    for (int j = 0; j < 8; ++j) {
      float a = T0f[j][0] * v[0];
#pragma unroll
      for (int k = 1; k < 8; ++k) a = fmaf(T0f[j][k], v[k], a);
      q[j] = a;
    }

    // ---- pack r-pairs to f16x2 and stage to LDS ----
    int4 qp;
    qp.x = h2i(pkrtz(q[0], q[1]));
    qp.y = h2i(pkrtz(q[2], q[3]));
    qp.z = h2i(pkrtz(q[4], q[5]));
    qp.w = h2i(pkrtz(q[6], q[7]));
    exA[w][l] = qp;   // row (j1,j2)

    // ---- chain-1 contraction: read rows (k, j2), weight by T1[j1,k] ----
    // Same-wave DS ops complete in program order; no barrier needed.
    h2 acc1[4] = {h2{0,0}, h2{0,0}, h2{0,0}, h2{0,0}};
#pragma unroll
    for (int g4 = 0; g4 < 2; ++g4) {
      int4 g[4];
#pragma unroll
      for (int k = 0; k < 4; ++k) g[k] = exA[w][((g4 * 4 + k) << 3) | j2];
#pragma unroll
      for (int k = 0; k < 4; ++k) {
        const h2 tk = T1h[g4 * 4 + k];
        acc1[0] += tk * ih2(g[k].x);
        acc1[1] += tk * ih2(g[k].y);
        acc1[2] += tk * ih2(g[k].z);
        acc1[3] += tk * ih2(g[k].w);
      }
    }

    // ---- stage chain-1 output, chain-2: read rows (j1, k), weight T2[j2,k] ----
    int4 ap;
    ap.x = h2i(acc1[0]); ap.y = h2i(acc1[1]);
    ap.z = h2i(acc1[2]); ap.w = h2i(acc1[3]);
    exB[w][l] = ap;

    h2 acc2[4] = {h2{0,0}, h2{0,0}, h2{0,0}, h2{0,0}};
#pragma unroll
    for (int g4 = 0; g4 < 2; ++g4) {
      int4 g[4];
#pragma unroll
      for (int k = 0; k < 4; ++k) g[k] = exB[w][(j1 << 3) | (g4 * 4 + k)];
#pragma unroll
      for (int k = 0; k < 4; ++k) {
        const h2 tk = T2h[g4 * 4 + k];
        acc2[0] += tk * ih2(g[k].x);
        acc2[1] += tk * ih2(g[k].y);
        acc2[2] += tk * ih2(g[k].z);
        acc2[3] += tk * ih2(g[k].w);
      }
    }

    // ---- unpack ----
    float wv[8];
#pragma unroll
    for (int p = 0; p < 4; ++p) {
      wv[2 * p]     = (float)acc2[p].x;
      wv[2 * p + 1] = (float)acc2[p].y;
    }

    // ---- emission multiply with max-shift, then renormalize ----
    float c = 0.f;
#pragma unroll
    for (int r = 0; r < 8; ++r) {
      float tl = wv[r] * __expf(e[r] - me);
      v[r] = tl;
      c = fmaxf(c, tl);
    }
    c = wave_max_dpp(c);
    const float rinv = __builtin_amdgcn_rcpf(c);
#pragma unroll
    for (int r = 0; r < 8; ++r) v[r] *= rinv;

    if (t >= tstart) {
      zacc += (double)(__logf(c) + me);
      ctsum += lgam[xi.x] + lgam[xi.y] + lgam[xi.z] + lgam[xi.w];
    }
  }

  if (chunk == NCHUNK - 1) {
    float s = 0.f;
#pragma unroll
    for (int r = 0; r < 8; ++r) s += v[r];
    s = wave_reduce_sum(s);
    zacc += (double)__logf(s);
  }

  if (l == 0) atomicAdd(accum, zacc - (double)ctsum);
}

__global__ void zero_acc_kernel(double* acc) {
  if (threadIdx.x == 0) *acc = 0.0;
}
__global__ void finalize_kernel(const double* __restrict__ acc,
                                float* __restrict__ out) {
  if (threadIdx.x == 0) out[0] = (float)(*acc);
}

extern "C" void kernel_launch(void* const* d_in, const int* in_sizes, int n_in,
                              void* d_out, int out_size, void* d_ws, size_t ws_size,
                              hipStream_t stream) {
  const int*   x     = (const int*)d_in[0];
  const float* lam0  = (const float*)d_in[1];
  const float* lam1  = (const float*)d_in[2];
  const float* lam2  = (const float*)d_in[3];
  const float* logA0 = (const float*)d_in[4];
  const float* logA1 = (const float*)d_in[5];
  const float* logA2 = (const float*)d_in[6];
  const float* logp0 = (const float*)d_in[7];
  const float* logp1 = (const float*)d_in[8];
  const float* logp2 = (const float*)d_in[9];
  double* acc = (double*)d_ws;
  float*  out = (float*)d_out;

  zero_acc_kernel<<<1, 64, 0, stream>>>(acc);
  hmm_fwd_chunk<<<NCHUNK / 4, 256, 0, stream>>>(x, lam0, lam1, lam2,
                                                logA0, logA1, logA2,
                                                logp0, logp1, logp2, acc);
  finalize_kernel<<<1, 64, 0, stream>>>(acc, out);
}

// Round 8
// 83.299 us; speedup vs baseline: 5.3176x; 1.0501x over previous
//
#include <hip/hip_runtime.h>

// Factorial HMM forward (3 chains x 8 states = 512 states, M=4, T=65536).
// Probability-domain scaled forward recurrence, all three 8x8 contractions in
// packed f16: chain-0 in-lane (pk_fma over dup-packed v), chains 1/2 via
// LDS-staged b128 exchange. Chunk-parallel over T with burn-in.
// R8: (1) exB transposed -> bank-conflict-free chain-2 reads (was 8-way,
// 2.62M conflict cycles); (2) chain-0 packed f16 (64 f32 fma -> 32 pk_fma,
// -32 VGPR); (3) tables built once in setup kernel (log2-space emission;
// v_exp/v_log are base-2 native); (4) 512-thr blocks (8 waves) as residency
// probe; BURN 2 (absmax was 0.0 at BURN=4 -> huge contraction margin).

#define NCHUNK 4096
#define CLEN   16          // NCHUNK * CLEN == 65536
#define BURN   2
#define WPB    8           // waves per block
#define NBLK   (NCHUNK / WPB)

// d_ws layout (bytes):
#define WS_T0   16         // int T0p[32]: [p*8+k] = (T0[2p][k], T0[2p+1][k]) f16x2
#define WS_T1   144        // int T1p[64]: [j*8+k] = dup(T1[j][k])
#define WS_T2   400        // int T2p[64]: [j*8+k] = dup(T2[j][k])
#define WS_LT   1024       // float Lt2[512][4]: log2(lamC[s][m]), s=r*64+j1*8+j2
#define WS_SL   9216       // float sl2[512]: sum_m lamC / ln2

typedef _Float16 h2 __attribute__((ext_vector_type(2)));
static __device__ __forceinline__ int h2i(h2 v) { return __builtin_bit_cast(int, v); }
static __device__ __forceinline__ h2 ih2(int v) { return __builtin_bit_cast(h2, v); }
static __device__ __forceinline__ h2 pkrtz(float a, float b) {
  return __builtin_bit_cast(h2, __builtin_amdgcn_cvt_pkrtz(a, b));
}

// Wave(64)-wide max via DPP butterfly on the VALU pipe (no DS ops).
static __device__ __forceinline__ float wave_max_dpp(float x) {
  int r = __builtin_bit_cast(int, x);
  auto mx = [](int a, int b) {
    return __builtin_bit_cast(
        int, fmaxf(__builtin_bit_cast(float, a), __builtin_bit_cast(float, b)));
  };
  int t;
  t = __builtin_amdgcn_update_dpp(r, r, 0x111, 0xf, 0xf, false); r = mx(r, t);
  t = __builtin_amdgcn_update_dpp(r, r, 0x112, 0xf, 0xf, false); r = mx(r, t);
  t = __builtin_amdgcn_update_dpp(r, r, 0x114, 0xf, 0xf, false); r = mx(r, t);
  t = __builtin_amdgcn_update_dpp(r, r, 0x118, 0xf, 0xf, false); r = mx(r, t);
  t = __builtin_amdgcn_update_dpp(r, r, 0x142, 0xa, 0xf, false); r = mx(r, t);
  t = __builtin_amdgcn_update_dpp(r, r, 0x143, 0xc, 0xf, false); r = mx(r, t);
  return __builtin_bit_cast(float, __builtin_amdgcn_readlane(r, 63));
}

__device__ __forceinline__ float wave_reduce_sum(float v) {
#pragma unroll
  for (int m = 32; m >= 1; m >>= 1) v += __shfl_xor(v, m, 64);
  return v;
}

// Build transition/emission tables once (also zeroes the accumulator).
__global__ void setup_kernel(const float* __restrict__ lam0,
                             const float* __restrict__ lam1,
                             const float* __restrict__ lam2,
                             const float* __restrict__ logA0,
                             const float* __restrict__ logA1,
                             const float* __restrict__ logA2,
                             char* __restrict__ ws) {
  const int tid = threadIdx.x;
  if (tid == 0) *(double*)ws = 0.0;
  int* T0p = (int*)(ws + WS_T0);
  int* T1p = (int*)(ws + WS_T1);
  int* T2p = (int*)(ws + WS_T2);
  float* Lt2 = (float*)(ws + WS_LT);
  float* sl2 = (float*)(ws + WS_SL);

  if (tid < 8) {            // T0 column tid
    const int k = tid;
    float m = logA0[k];
    for (int j = 1; j < 8; ++j) m = fmaxf(m, logA0[j * 8 + k]);
    float p[8], s = 0.f;
    for (int j = 0; j < 8; ++j) { p[j] = __expf(logA0[j * 8 + k] - m); s += p[j]; }
    const float inv = 1.f / s;
    for (int pp = 0; pp < 4; ++pp)
      T0p[pp * 8 + k] = h2i(pkrtz(p[2 * pp] * inv, p[2 * pp + 1] * inv));
  } else if (tid < 16) {    // T1 column
    const int k = tid - 8;
    float m = logA1[k];
    for (int j = 1; j < 8; ++j) m = fmaxf(m, logA1[j * 8 + k]);
    float p[8], s = 0.f;
    for (int j = 0; j < 8; ++j) { p[j] = __expf(logA1[j * 8 + k] - m); s += p[j]; }
    const float inv = 1.f / s;
    for (int j = 0; j < 8; ++j) { float t = p[j] * inv; T1p[j * 8 + k] = h2i(pkrtz(t, t)); }
  } else if (tid < 24) {    // T2 column
    const int k = tid - 16;
    float m = logA2[k];
    for (int j = 1; j < 8; ++j) m = fmaxf(m, logA2[j * 8 + k]);
    float p[8], s = 0.f;
    for (int j = 0; j < 8; ++j) { p[j] = __expf(logA2[j * 8 + k] - m); s += p[j]; }
    const float inv = 1.f / s;
    for (int j = 0; j < 8; ++j) { float t = p[j] * inv; T2p[j * 8 + k] = h2i(pkrtz(t, t)); }
  }
  // all 512 threads: emission tables for state tid = r*64 + j1*8 + j2
  const int r = tid >> 6, j1 = (tid >> 3) & 7, j2 = tid & 7;
  float sl = 0.f;
  for (int m = 0; m < 4; ++m) {
    const float lam = lam0[r * 4 + m] + lam1[j1 * 4 + m] + lam2[j2 * 4 + m];
    Lt2[tid * 4 + m] = __log2f(lam);
    sl += lam;
  }
  sl2[tid] = sl * 1.44269504f;   // sumLam / ln2
}

__global__ __launch_bounds__(512, 1)
void hmm_fwd_chunk(const int* __restrict__ x,
                   const float* __restrict__ logp0, const float* __restrict__ logp1,
                   const float* __restrict__ logp2,
                   const char* __restrict__ ws, double* __restrict__ accum)
{
  const int l = threadIdx.x & 63;                          // lane 0..63
  const int w = threadIdx.x >> 6;                          // wave 0..7
  const int chunk = blockIdx.x * WPB + w;                  // 0..NCHUNK-1
  const int j1 = l >> 3;
  const int j2 = l & 7;

  __shared__ float lgam[20];
  __shared__ int4 exA[WPB][64];    // rows (j1<<3)|j2
  __shared__ int4 exB[WPB][64];    // TRANSPOSED rows (j2<<3)|j1
  if (threadIdx.x == 0) {
    lgam[0]  = 0.0f;          lgam[1]  = 0.0f;
    lgam[2]  = 0.69314718f;   lgam[3]  = 1.79175947f;
    lgam[4]  = 3.17805383f;   lgam[5]  = 4.78749174f;
    lgam[6]  = 6.57925121f;   lgam[7]  = 8.52516136f;
    lgam[8]  = 10.60460290f;  lgam[9]  = 12.80182748f;
    lgam[10] = 15.10441257f;  lgam[11] = 17.50230785f;
    lgam[12] = 19.98721450f;  lgam[13] = 22.55216385f;
    lgam[14] = 25.19122118f;  lgam[15] = 27.89927138f;
    lgam[16] = 30.67186011f;  lgam[17] = 33.50507345f;
    lgam[18] = 36.39544521f;  lgam[19] = 39.33988419f;
  }
  __syncthreads();

  // ---- load tables from ws ----
  int T0r[32];
  {
    const int4* p = (const int4*)(ws + WS_T0);
#pragma unroll
    for (int i = 0; i < 8; ++i) {
      const int4 g = p[i];
      T0r[4 * i] = g.x; T0r[4 * i + 1] = g.y; T0r[4 * i + 2] = g.z; T0r[4 * i + 3] = g.w;
    }
  }
  int T1r[8];
  {
    const int4* p = (const int4*)(ws + WS_T1) + j1 * 2;
    const int4 a = p[0], b = p[1];
    T1r[0] = a.x; T1r[1] = a.y; T1r[2] = a.z; T1r[3] = a.w;
    T1r[4] = b.x; T1r[5] = b.y; T1r[6] = b.z; T1r[7] = b.w;
  }
  int T2r[8];
  {
    const int4* p = (const int4*)(ws + WS_T2) + j2 * 2;
    const int4 a = p[0], b = p[1];
    T2r[0] = a.x; T2r[1] = a.y; T2r[2] = a.z; T2r[3] = a.w;
    T2r[4] = b.x; T2r[5] = b.y; T2r[6] = b.z; T2r[7] = b.w;
  }
  float Ltr[8][4], slr[8];
  {
    const float4* lt = (const float4*)(ws + WS_LT);
    const float* sl = (const float*)(ws + WS_SL);
#pragma unroll
    for (int r = 0; r < 8; ++r) {
      const float4 g = lt[r * 64 + l];
      Ltr[r][0] = g.x; Ltr[r][1] = g.y; Ltr[r][2] = g.z; Ltr[r][3] = g.w;
      slr[r] = sl[r * 64 + l];
    }
  }

  const int tstart = chunk * CLEN;
  const int tend = tstart + CLEN;

  h2 vdup[8];          // message, max-normalized, dup-packed per state r
  float zacc = 0.f;    // per-chunk log2-normalizer sum
  float ctsum = 0.f;   // per-chunk sum of wave-uniform lgamma terms (natural)
  int t0;

  // emission log2-prob excluding the wave-uniform lgamma term
  auto emis2 = [&](const int4 xi, float e[8]) {
    const float xf0 = (float)xi.x, xf1 = (float)xi.y,
                xf2 = (float)xi.z, xf3 = (float)xi.w;
#pragma unroll
    for (int r = 0; r < 8; ++r) {
      float a = -slr[r];
      a = fmaf(xf0, Ltr[r][0], a);
      a = fmaf(xf1, Ltr[r][1], a);
      a = fmaf(xf2, Ltr[r][2], a);
      a = fmaf(xf3, Ltr[r][3], a);
      e[r] = a;
    }
  };

  if (chunk == 0) {
    // exact init from prior at t=0 (log2 space)
    const float L2E = 1.44269504f;
    float lp0[8];
    {
      float m = logp0[0];
#pragma unroll
      for (int j = 1; j < 8; ++j) m = fmaxf(m, logp0[j]);
      float s = 0.f;
#pragma unroll
      for (int j = 0; j < 8; ++j) s += __expf(logp0[j] - m);
      const float lg = m + __logf(s);
#pragma unroll
      for (int j = 0; j < 8; ++j) lp0[j] = logp0[j] - lg;
    }
    float lp1v, lp2v;
    {
      float m = logp1[0];
#pragma unroll
      for (int j = 1; j < 8; ++j) m = fmaxf(m, logp1[j]);
      float s = 0.f;
#pragma unroll
      for (int j = 0; j < 8; ++j) s += __expf(logp1[j] - m);
      lp1v = logp1[j1] - (m + __logf(s));
    }
    {
      float m = logp2[0];
#pragma unroll
      for (int j = 1; j < 8; ++j) m = fmaxf(m, logp2[j]);
      float s = 0.f;
#pragma unroll
      for (int j = 0; j < 8; ++j) s += __expf(logp2[j] - m);
      lp2v = logp2[j2] - (m + __logf(s));
    }
    const int4 xi0 = *reinterpret_cast<const int4*>(x);
    float e[8];
    emis2(xi0, e);
    ctsum = lgam[xi0.x] + lgam[xi0.y] + lgam[xi0.z] + lgam[xi0.w];
    float a2[8];
    float mx = -3.0e38f;
#pragma unroll
    for (int r = 0; r < 8; ++r) {
      a2[r] = (lp0[r] + lp1v + lp2v) * L2E + e[r];
      mx = fmaxf(mx, a2[r]);
    }
    mx = wave_max_dpp(mx);
#pragma unroll
    for (int r = 0; r < 8; ++r) {
      const float vv = exp2f(a2[r] - mx);
      vdup[r] = pkrtz(vv, vv);
    }
    zacc = mx;
    t0 = 1;
  } else {
    // burn-in from a uniform (unnormalized) message
#pragma unroll
    for (int r = 0; r < 8; ++r) vdup[r] = pkrtz(1.f, 1.f);
    t0 = tstart - BURN;
  }

  // merged burn-in + accumulate loop, x prefetched one step ahead
  int4 xi_next = *reinterpret_cast<const int4*>(x + 4 * t0);
  for (int t = t0; t < tend; ++t) {
    const int4 xi = xi_next;
    if (t + 1 < tend)
      xi_next = *reinterpret_cast<const int4*>(x + 4 * (t + 1));

    // emission + wave max (independent of v; overlaps mixing latency)
    float e[8];
    emis2(xi, e);
    float me = e[0];
#pragma unroll
    for (int r = 1; r < 8; ++r) me = fmaxf(me, e[r]);
    me = wave_max_dpp(me);

    // ---- chain-0: in-lane packed contraction over r ----
    h2 q[4];
#pragma unroll
    for (int p = 0; p < 4; ++p) {
      h2 a = ih2(T0r[p * 8]) * vdup[0];
#pragma unroll
      for (int k = 1; k < 8; ++k) a += ih2(T0r[p * 8 + k]) * vdup[k];
      q[p] = a;
    }
    exA[w][l] = int4{h2i(q[0]), h2i(q[1]), h2i(q[2]), h2i(q[3])};

    // ---- chain-1: read rows (k, j2), weight dup(T1[j1,k]) ----
    // byte addr = k*128 + j2*16: j2 varies across lanes -> conflict-free
    h2 acc1[4] = {h2{0, 0}, h2{0, 0}, h2{0, 0}, h2{0, 0}};
#pragma unroll
    for (int g4 = 0; g4 < 2; ++g4) {
      int4 g[4];
#pragma unroll
      for (int k = 0; k < 4; ++k) g[k] = exA[w][((g4 * 4 + k) << 3) | j2];
#pragma unroll
      for (int k = 0; k < 4; ++k) {
        const h2 tk = ih2(T1r[g4 * 4 + k]);
        acc1[0] += tk * ih2(g[k].x);
        acc1[1] += tk * ih2(g[k].y);
        acc1[2] += tk * ih2(g[k].z);
        acc1[3] += tk * ih2(g[k].w);
      }
    }

    // ---- chain-2: TRANSPOSED staging; read rows (k<<3)|j1 ----
    // byte addr = k*128 + j1*16: j1 varies across lanes -> conflict-free
    exB[w][(j2 << 3) | j1] = int4{h2i(acc1[0]), h2i(acc1[1]), h2i(acc1[2]), h2i(acc1[3])};

    h2 acc2[4] = {h2{0, 0}, h2{0, 0}, h2{0, 0}, h2{0, 0}};
#pragma unroll
    for (int g4 = 0; g4 < 2; ++g4) {
      int4 g[4];
#pragma unroll
      for (int k = 0; k < 4; ++k) g[k] = exB[w][((g4 * 4 + k) << 3) | j1];
#pragma unroll
      for (int k = 0; k < 4; ++k) {
        const h2 tk = ih2(T2r[g4 * 4 + k]);
        acc2[0] += tk * ih2(g[k].x);
        acc2[1] += tk * ih2(g[k].y);
        acc2[2] += tk * ih2(g[k].z);
        acc2[3] += tk * ih2(g[k].w);
      }
    }

    // ---- emission multiply (log2 space) + max-renormalize ----
    float tl[8];
    float c = 0.f;
#pragma unroll
    for (int p = 0; p < 4; ++p) {
      const float w0 = (float)acc2[p].x, w1 = (float)acc2[p].y;
      const float t0f = w0 * exp2f(e[2 * p] - me);
      const float t1f = w1 * exp2f(e[2 * p + 1] - me);
      tl[2 * p] = t0f; tl[2 * p + 1] = t1f;
      c = fmaxf(c, fmaxf(t0f, t1f));
    }
    c = wave_max_dpp(c);
    const float rinv = __builtin_amdgcn_rcpf(c);
#pragma unroll
    for (int r = 0; r < 8; ++r) {
      const float vn = tl[r] * rinv;
      vdup[r] = pkrtz(vn, vn);
    }

    if (t >= tstart) {
      zacc += __log2f(c) + me;
      ctsum += lgam[xi.x] + lgam[xi.y] + lgam[xi.z] + lgam[xi.w];
    }
  }

  if (chunk == NCHUNK - 1) {
    float s = 0.f;
#pragma unroll
    for (int r = 0; r < 8; ++r) s += (float)vdup[r].x;
    s = wave_reduce_sum(s);
    zacc += __log2f(s);
  }

  if (l == 0)
    atomicAdd(accum, (double)zacc * 0.6931471805599453 - (double)ctsum);
}

__global__ void finalize_kernel(const double* __restrict__ acc,
                                float* __restrict__ out) {
  if (threadIdx.x == 0) out[0] = (float)(*acc);
}

extern "C" void kernel_launch(void* const* d_in, const int* in_sizes, int n_in,
                              void* d_out, int out_size, void* d_ws, size_t ws_size,
                              hipStream_t stream) {
  const int*   x     = (const int*)d_in[0];
  const float* lam0  = (const float*)d_in[1];
  const float* lam1  = (const float*)d_in[2];
  const float* lam2  = (const float*)d_in[3];
  const float* logA0 = (const float*)d_in[4];
  const float* logA1 = (const float*)d_in[5];
  const float* logA2 = (const float*)d_in[6];
  const float* logp0 = (const float*)d_in[7];
  const float* logp1 = (const float*)d_in[8];
  const float* logp2 = (const float*)d_in[9];
  float* out = (float*)d_out;

  setup_kernel<<<1, 512, 0, stream>>>(lam0, lam1, lam2, logA0, logA1, logA2,
                                      (char*)d_ws);
  hmm_fwd_chunk<<<NBLK, 512, 0, stream>>>(x, logp0, logp1, logp2,
                                          (const char*)d_ws, (double*)d_ws);
  finalize_kernel<<<1, 64, 0, stream>>>((const double*)d_ws, out);
}

// Round 9
// 68.419 us; speedup vs baseline: 6.4741x; 1.2175x over previous
//
#include <hip/hip_runtime.h>

// Factorial HMM forward (3 chains x 8 states = 512 states, M=4, T=65536).
// Probability-domain scaled forward recurrence, all three 8x8 contractions in
// packed f16: chain-0 in-lane (pk_fma over dup-packed v), chains 1/2 via
// LDS-staged b128 exchange. Chunk-parallel over T with burn-in.
// R9: (1) TWO independent chunks per wave (A/B), fused interleaved step ->
// in-wave ILP hides DS/DPP/reload latency (was 2500 cy/step serial);
// (2) exB stride-9 rows: write bank group 4*(j1+j2) -> <=2-way (R8's
// transpose made the WRITE 8-way: bank 4*j1 only); (3) per-slot __shared__
// arrays (no aliasing). Tables from setup kernel; log2-space emission.

#define NCHUNK 4096
#define CLEN   16          // NCHUNK * CLEN == 65536
#define BURN   2
#define STEPS  (CLEN + BURN)
#define WPB    4           // waves per block (256 thr)
#define NWAVE  (NCHUNK / 2)
#define NBLK   (NWAVE / WPB)

// d_ws layout (bytes):
#define WS_T0   16         // int T0p[32]: [p*8+k] = (T0[2p][k], T0[2p+1][k]) f16x2
#define WS_T1   144        // int T1p[64]: [j*8+k] = dup(T1[j][k])
#define WS_T2   400        // int T2p[64]: [j*8+k] = dup(T2[j][k])
#define WS_LT   1024       // float Lt2[512][4]: log2(lamC[s][m]), s=r*64+j1*8+j2
#define WS_SL   9216       // float sl2[512]: sum_m lamC / ln2

typedef _Float16 h2 __attribute__((ext_vector_type(2)));
static __device__ __forceinline__ int h2i(h2 v) { return __builtin_bit_cast(int, v); }
static __device__ __forceinline__ h2 ih2(int v) { return __builtin_bit_cast(h2, v); }
static __device__ __forceinline__ h2 pkrtz(float a, float b) {
  return __builtin_bit_cast(h2, __builtin_amdgcn_cvt_pkrtz(a, b));
}

// Wave(64)-wide max via DPP butterfly on the VALU pipe (no DS ops).
static __device__ __forceinline__ float wave_max_dpp(float x) {
  int r = __builtin_bit_cast(int, x);
  auto mx = [](int a, int b) {
    return __builtin_bit_cast(
        int, fmaxf(__builtin_bit_cast(float, a), __builtin_bit_cast(float, b)));
  };
  int t;
  t = __builtin_amdgcn_update_dpp(r, r, 0x111, 0xf, 0xf, false); r = mx(r, t);
  t = __builtin_amdgcn_update_dpp(r, r, 0x112, 0xf, 0xf, false); r = mx(r, t);
  t = __builtin_amdgcn_update_dpp(r, r, 0x114, 0xf, 0xf, false); r = mx(r, t);
  t = __builtin_amdgcn_update_dpp(r, r, 0x118, 0xf, 0xf, false); r = mx(r, t);
  t = __builtin_amdgcn_update_dpp(r, r, 0x142, 0xa, 0xf, false); r = mx(r, t);
  t = __builtin_amdgcn_update_dpp(r, r, 0x143, 0xc, 0xf, false); r = mx(r, t);
  return __builtin_bit_cast(float, __builtin_amdgcn_readlane(r, 63));
}

__device__ __forceinline__ float wave_reduce_sum(float v) {
#pragma unroll
  for (int m = 32; m >= 1; m >>= 1) v += __shfl_xor(v, m, 64);
  return v;
}

// Build transition/emission tables once (also zeroes the accumulator).
__global__ void setup_kernel(const float* __restrict__ lam0,
                             const float* __restrict__ lam1,
                             const float* __restrict__ lam2,
                             const float* __restrict__ logA0,
                             const float* __restrict__ logA1,
                             const float* __restrict__ logA2,
                             char* __restrict__ ws) {
  const int tid = threadIdx.x;
  if (tid == 0) *(double*)ws = 0.0;
  int* T0p = (int*)(ws + WS_T0);
  int* T1p = (int*)(ws + WS_T1);
  int* T2p = (int*)(ws + WS_T2);
  float* Lt2 = (float*)(ws + WS_LT);
  float* sl2 = (float*)(ws + WS_SL);

  if (tid < 8) {            // T0 column tid
    const int k = tid;
    float m = logA0[k];
    for (int j = 1; j < 8; ++j) m = fmaxf(m, logA0[j * 8 + k]);
    float p[8], s = 0.f;
    for (int j = 0; j < 8; ++j) { p[j] = __expf(logA0[j * 8 + k] - m); s += p[j]; }
    const float inv = 1.f / s;
    for (int pp = 0; pp < 4; ++pp)
      T0p[pp * 8 + k] = h2i(pkrtz(p[2 * pp] * inv, p[2 * pp + 1] * inv));
  } else if (tid < 16) {    // T1 column
    const int k = tid - 8;
    float m = logA1[k];
    for (int j = 1; j < 8; ++j) m = fmaxf(m, logA1[j * 8 + k]);
    float p[8], s = 0.f;
    for (int j = 0; j < 8; ++j) { p[j] = __expf(logA1[j * 8 + k] - m); s += p[j]; }
    const float inv = 1.f / s;
    for (int j = 0; j < 8; ++j) { float t = p[j] * inv; T1p[j * 8 + k] = h2i(pkrtz(t, t)); }
  } else if (tid < 24) {    // T2 column
    const int k = tid - 16;
    float m = logA2[k];
    for (int j = 1; j < 8; ++j) m = fmaxf(m, logA2[j * 8 + k]);
    float p[8], s = 0.f;
    for (int j = 0; j < 8; ++j) { p[j] = __expf(logA2[j * 8 + k] - m); s += p[j]; }
    const float inv = 1.f / s;
    for (int j = 0; j < 8; ++j) { float t = p[j] * inv; T2p[j * 8 + k] = h2i(pkrtz(t, t)); }
  }
  // all 512 threads: emission tables for state tid = r*64 + j1*8 + j2
  const int r = tid >> 6, j1 = (tid >> 3) & 7, j2 = tid & 7;
  float sl = 0.f;
  for (int m = 0; m < 4; ++m) {
    const float lam = lam0[r * 4 + m] + lam1[j1 * 4 + m] + lam2[j2 * 4 + m];
    Lt2[tid * 4 + m] = __log2f(lam);
    sl += lam;
  }
  sl2[tid] = sl * 1.44269504f;   // sumLam / ln2
}

__global__ __launch_bounds__(256)
void hmm_fwd_chunk(const int* __restrict__ x,
                   const float* __restrict__ logp0, const float* __restrict__ logp1,
                   const float* __restrict__ logp2,
                   const char* __restrict__ ws, double* __restrict__ accum)
{
  const int l = threadIdx.x & 63;                   // lane 0..63
  const int w = threadIdx.x >> 6;                   // wave 0..3
  const int gw = blockIdx.x * WPB + w;              // 0..NWAVE-1
  const int cA = gw * 2, cB = cA + 1;               // this wave's two chunks
  const int j1 = l >> 3;
  const int j2 = l & 7;

  __shared__ float lgam[20];
  __shared__ int4 sA0[WPB][64], sB0[WPB][64];   // chain-1 staging, rows (j1<<3)|j2
  __shared__ int4 sA1[WPB][72], sB1[WPB][72];   // chain-2 staging, rows j2*9+j1
  if (threadIdx.x == 0) {
    lgam[0]  = 0.0f;          lgam[1]  = 0.0f;
    lgam[2]  = 0.69314718f;   lgam[3]  = 1.79175947f;
    lgam[4]  = 3.17805383f;   lgam[5]  = 4.78749174f;
    lgam[6]  = 6.57925121f;   lgam[7]  = 8.52516136f;
    lgam[8]  = 10.60460290f;  lgam[9]  = 12.80182748f;
    lgam[10] = 15.10441257f;  lgam[11] = 17.50230785f;
    lgam[12] = 19.98721450f;  lgam[13] = 22.55216385f;
    lgam[14] = 25.19122118f;  lgam[15] = 27.89927138f;
    lgam[16] = 30.67186011f;  lgam[17] = 33.50507345f;
    lgam[18] = 36.39544521f;  lgam[19] = 39.33988419f;
  }
  __syncthreads();

  int4* bA0 = sA0[w]; int4* bB0 = sB0[w];
  int4* bA1 = sA1[w]; int4* bB1 = sB1[w];

  // ---- load tables from ws ----
  int T0r[32];
  {
    const int4* p = (const int4*)(ws + WS_T0);
#pragma unroll
    for (int i = 0; i < 8; ++i) {
      const int4 g = p[i];
      T0r[4 * i] = g.x; T0r[4 * i + 1] = g.y; T0r[4 * i + 2] = g.z; T0r[4 * i + 3] = g.w;
    }
  }
  int T1r[8];
  {
    const int4* p = (const int4*)(ws + WS_T1) + j1 * 2;
    const int4 a = p[0], b = p[1];
    T1r[0] = a.x; T1r[1] = a.y; T1r[2] = a.z; T1r[3] = a.w;
    T1r[4] = b.x; T1r[5] = b.y; T1r[6] = b.z; T1r[7] = b.w;
  }
  int T2r[8];
  {
    const int4* p = (const int4*)(ws + WS_T2) + j2 * 2;
    const int4 a = p[0], b = p[1];
    T2r[0] = a.x; T2r[1] = a.y; T2r[2] = a.z; T2r[3] = a.w;
    T2r[4] = b.x; T2r[5] = b.y; T2r[6] = b.z; T2r[7] = b.w;
  }
  float Ltr[8][4], slr[8];
  {
    const float4* lt = (const float4*)(ws + WS_LT);
    const float* sl = (const float*)(ws + WS_SL);
#pragma unroll
    for (int r = 0; r < 8; ++r) {
      const float4 g = lt[r * 64 + l];
      Ltr[r][0] = g.x; Ltr[r][1] = g.y; Ltr[r][2] = g.z; Ltr[r][3] = g.w;
      slr[r] = sl[r * 64 + l];
    }
  }

  const int tsA = cA * CLEN, teA = tsA + CLEN;
  const int tsB = cB * CLEN;

  // emission log2-prob excluding the wave-uniform lgamma term
  auto emis2 = [&](const int4 xi, float (&e)[8]) {
    const float xf0 = (float)xi.x, xf1 = (float)xi.y,
                xf2 = (float)xi.z, xf3 = (float)xi.w;
#pragma unroll
    for (int r = 0; r < 8; ++r) {
      float a = -slr[r];
      a = fmaf(xf0, Ltr[r][0], a);
      a = fmaf(xf1, Ltr[r][1], a);
      a = fmaf(xf2, Ltr[r][2], a);
      a = fmaf(xf3, Ltr[r][3], a);
      e[r] = a;
    }
  };
  auto chain0 = [&](const h2 (&vd)[8]) -> int4 {
    h2 q0 = ih2(T0r[0]) * vd[0], q1 = ih2(T0r[8]) * vd[0],
       q2 = ih2(T0r[16]) * vd[0], q3 = ih2(T0r[24]) * vd[0];
#pragma unroll
    for (int k = 1; k < 8; ++k) {
      q0 += ih2(T0r[k]) * vd[k];
      q1 += ih2(T0r[8 + k]) * vd[k];
      q2 += ih2(T0r[16 + k]) * vd[k];
      q3 += ih2(T0r[24 + k]) * vd[k];
    }
    return int4{h2i(q0), h2i(q1), h2i(q2), h2i(q3)};
  };
  // chain-1: read rows (k, j2) at stride 8; conflict-free (addr 128k+16*j2)
  auto mix1 = [&](const int4* buf) -> int4 {
    h2 a0{0, 0}, a1{0, 0}, a2{0, 0}, a3{0, 0};
#pragma unroll
    for (int g4 = 0; g4 < 2; ++g4) {
      int4 g[4];
#pragma unroll
      for (int k = 0; k < 4; ++k) g[k] = buf[((g4 * 4 + k) << 3) | j2];
#pragma unroll
      for (int k = 0; k < 4; ++k) {
        const h2 tk = ih2(T1r[g4 * 4 + k]);
        a0 += tk * ih2(g[k].x); a1 += tk * ih2(g[k].y);
        a2 += tk * ih2(g[k].z); a3 += tk * ih2(g[k].w);
      }
    }
    return int4{h2i(a0), h2i(a1), h2i(a2), h2i(a3)};
  };
  // chain-2: read rows k*9+j1 (stride-9 pad); addr 144k+16*j1 -> broadcast
  auto mix2 = [&](const int4* buf) -> int4 {
    h2 a0{0, 0}, a1{0, 0}, a2{0, 0}, a3{0, 0};
#pragma unroll
    for (int g4 = 0; g4 < 2; ++g4) {
      int4 g[4];
#pragma unroll
      for (int k = 0; k < 4; ++k) g[k] = buf[(g4 * 4 + k) * 9 + j1];
#pragma unroll
      for (int k = 0; k < 4; ++k) {
        const h2 tk = ih2(T2r[g4 * 4 + k]);
        a0 += tk * ih2(g[k].x); a1 += tk * ih2(g[k].y);
        a2 += tk * ih2(g[k].z); a3 += tk * ih2(g[k].w);
      }
    }
    return int4{h2i(a0), h2i(a1), h2i(a2), h2i(a3)};
  };
  auto finishf = [&](const int4 av, const float (&e)[8], const float me,
                     float (&tl)[8]) -> float {
    const int ai[4] = {av.x, av.y, av.z, av.w};
    float c = 0.f;
#pragma unroll
    for (int p = 0; p < 4; ++p) {
      const h2 ap = ih2(ai[p]);
      const float t0f = (float)ap.x * exp2f(e[2 * p] - me);
      const float t1f = (float)ap.y * exp2f(e[2 * p + 1] - me);
      tl[2 * p] = t0f; tl[2 * p + 1] = t1f;
      c = fmaxf(c, fmaxf(t0f, t1f));
    }
    return c;
  };

  h2 vA[8], vB[8];
  float zA = 0.f, zB = 0.f, ctA = 0.f, ctB = 0.f;
  int tA;

  if (cA == 0) {
    // exact init from prior at t=0 (log2 space)
    const float L2E = 1.44269504f;
    float lp0[8];
    {
      float m = logp0[0];
#pragma unroll
      for (int j = 1; j < 8; ++j) m = fmaxf(m, logp0[j]);
      float s = 0.f;
#pragma unroll
      for (int j = 0; j < 8; ++j) s += __expf(logp0[j] - m);
      const float lg = m + __logf(s);
#pragma unroll
      for (int j = 0; j < 8; ++j) lp0[j] = logp0[j] - lg;
    }
    float lp1v, lp2v;
    {
      float m = logp1[0];
#pragma unroll
      for (int j = 1; j < 8; ++j) m = fmaxf(m, logp1[j]);
      float s = 0.f;
#pragma unroll
      for (int j = 0; j < 8; ++j) s += __expf(logp1[j] - m);
      lp1v = logp1[j1] - (m + __logf(s));
    }
    {
      float m = logp2[0];
#pragma unroll
      for (int j = 1; j < 8; ++j) m = fmaxf(m, logp2[j]);
      float s = 0.f;
#pragma unroll
      for (int j = 0; j < 8; ++j) s += __expf(logp2[j] - m);
      lp2v = logp2[j2] - (m + __logf(s));
    }
    const int4 xi0 = *reinterpret_cast<const int4*>(x);
    float e[8];
    emis2(xi0, e);
    ctA = lgam[xi0.x] + lgam[xi0.y] + lgam[xi0.z] + lgam[xi0.w];
    float a2[8];
    float mx = -3.0e38f;
#pragma unroll
    for (int r = 0; r < 8; ++r) {
      a2[r] = (lp0[r] + lp1v + lp2v) * L2E + e[r];
      mx = fmaxf(mx, a2[r]);
    }
    mx = wave_max_dpp(mx);
#pragma unroll
    for (int r = 0; r < 8; ++r) {
      const float vv = exp2f(a2[r] - mx);
      vA[r] = pkrtz(vv, vv);
    }
    zA = mx;
    tA = 1;
  } else {
#pragma unroll
    for (int r = 0; r < 8; ++r) vA[r] = pkrtz(1.f, 1.f);
    tA = tsA - BURN;
  }
#pragma unroll
  for (int r = 0; r < 8; ++r) vB[r] = pkrtz(1.f, 1.f);
  int tB = tsB - BURN;

  int4 xA = *reinterpret_cast<const int4*>(x + 4 * tA);
  int4 xB = *reinterpret_cast<const int4*>(x + 4 * tB);

  for (int u = 0; u < STEPS; ++u, ++tA, ++tB) {
    const int4 xiA = xA, xiB = xB;
    if (u + 1 < STEPS) {
      xA = *reinterpret_cast<const int4*>(x + 4 * (tA + 1));
      xB = *reinterpret_cast<const int4*>(x + 4 * (tB + 1));
    }

    // emissions + wave maxes (independent of v; two streams interleave)
    float eA[8], eB[8];
    emis2(xiA, eA); emis2(xiB, eB);
    float meA = eA[0], meB = eB[0];
#pragma unroll
    for (int r = 1; r < 8; ++r) { meA = fmaxf(meA, eA[r]); meB = fmaxf(meB, eB[r]); }
    meA = wave_max_dpp(meA);
    meB = wave_max_dpp(meB);

    // chain-0 + stage (both streams issued before any consumption)
    bA0[l] = chain0(vA);
    bB0[l] = chain0(vB);

    // chain-1 (A's lgkm wait leaves B's reads in flight)
    const int4 hA = mix1(bA0);
    const int4 hB = mix1(bB0);
    bA1[j2 * 9 + j1] = hA;
    bB1[j2 * 9 + j1] = hB;

    // chain-2
    const int4 aA = mix2(bA1);
    const int4 aB = mix2(bB1);

    // finish: emission multiply (log2) + max-renormalize
    float tlA[8], tlB[8];
    float cA_ = finishf(aA, eA, meA, tlA);
    float cB_ = finishf(aB, eB, meB, tlB);
    cA_ = wave_max_dpp(cA_);
    cB_ = wave_max_dpp(cB_);
    const float rA = __builtin_amdgcn_rcpf(cA_);
    const float rB = __builtin_amdgcn_rcpf(cB_);
#pragma unroll
    for (int r = 0; r < 8; ++r) {
      const float na = tlA[r] * rA;
      const float nb = tlB[r] * rB;
      vA[r] = pkrtz(na, na);
      vB[r] = pkrtz(nb, nb);
    }

    if (tA >= tsA && tA < teA) {
      zA += __log2f(cA_) + meA;
      ctA += lgam[xiA.x] + lgam[xiA.y] + lgam[xiA.z] + lgam[xiA.w];
    }
    if (tB >= tsB) {
      zB += __log2f(cB_) + meB;
      ctB += lgam[xiB.x] + lgam[xiB.y] + lgam[xiB.z] + lgam[xiB.w];
    }
  }

  if (cB == NCHUNK - 1) {
    float s = 0.f;
#pragma unroll
    for (int r = 0; r < 8; ++r) s += (float)vB[r].x;
    s = wave_reduce_sum(s);
    zB += __log2f(s);
  }

  if (l == 0)
    atomicAdd(accum, ((double)zA + (double)zB) * 0.6931471805599453
                       - (double)ctA - (double)ctB);
}

__global__ void finalize_kernel(const double* __restrict__ acc,
                                float* __restrict__ out) {
  if (threadIdx.x == 0) out[0] = (float)(*acc);
}

extern "C" void kernel_launch(void* const* d_in, const int* in_sizes, int n_in,
                              void* d_out, int out_size, void* d_ws, size_t ws_size,
                              hipStream_t stream) {
  const int*   x     = (const int*)d_in[0];
  const float* lam0  = (const float*)d_in[1];
  const float* lam1  = (const float*)d_in[2];
  const float* lam2  = (const float*)d_in[3];
  const float* logA0 = (const float*)d_in[4];
  const float* logA1 = (const float*)d_in[5];
  const float* logA2 = (const float*)d_in[6];
  const float* logp0 = (const float*)d_in[7];
  const float* logp1 = (const float*)d_in[8];
  const float* logp2 = (const float*)d_in[9];
  float* out = (float*)d_out;

  setup_kernel<<<1, 512, 0, stream>>>(lam0, lam1, lam2, logA0, logA1, logA2,
                                      (char*)d_ws);
  hmm_fwd_chunk<<<NBLK, 256, 0, stream>>>(x, logp0, logp1, logp2,
                                          (const char*)d_ws, (double*)d_ws);
  finalize_kernel<<<1, 64, 0, stream>>>((const double*)d_ws, out);
}